// Round 16
// baseline (294.554 us; speedup 1.0000x reference)
//
#include <hip/hip_runtime.h>

#define EMB 384
#define HEADS 6
#define DH 64
#define TT 256

constexpr float SCALE = 0.05103103630798288f;  // 384^-0.5

typedef __attribute__((ext_vector_type(8))) short short8;
typedef __attribute__((ext_vector_type(4))) float f32x4;
typedef __attribute__((ext_vector_type(4))) unsigned short u16x4;

__device__ __forceinline__ unsigned short f2bf(float f) {
  unsigned int u = __builtin_bit_cast(unsigned int, f);
  u += 0x7FFFu + ((u >> 16) & 1u);   // RNE
  return (unsigned short)(u >> 16);
}
__device__ __forceinline__ float bf2f(unsigned short u) {
  unsigned int v = ((unsigned int)u) << 16;
  return __builtin_bit_cast(float, v);
}
__device__ __forceinline__ void gll16(const void* g, void* l) {
  __builtin_amdgcn_global_load_lds(
      (const __attribute__((address_space(1))) unsigned int*)g,
      (__attribute__((address_space(3))) unsigned int*)l, 16, 0, 0);
}

// ---- K0: build Wt[1536][384] bf16. Rows 0..1151: per-HEAD blocks of 192
// (q d0-63 | k d0-63 | v d0-63); rows 1152..1535: proj^T. ----
__global__ __launch_bounds__(256)
void build_wt(const float* __restrict__ Wq, const float* __restrict__ Wk,
              const float* __restrict__ Wv, const float* __restrict__ Wp,
              unsigned short* __restrict__ Wt) {
  int idx = blockIdx.x * 256 + threadIdx.x;  // 1536*48 = 73728
  int n = idx / 48, e0 = (idx % 48) * 8;
  const float* src; int stride;
  if (n < 1152) {
    int h = n / 192, rem = n % 192, qkv = rem >> 6, d = rem & 63;
    const float* W = (qkv == 0) ? Wq : (qkv == 1) ? Wk : Wv;
    src = W + ((size_t)h * EMB + e0) * DH + d; stride = DH;
  } else {
    int c = n - 1152;
    src = Wp + (size_t)e0 * EMB + c; stride = EMB;
  }
  short8 o;
  #pragma unroll
  for (int j = 0; j < 8; ++j) o[j] = (short)f2bf(src[j * stride]);
  ((short8*)Wt)[idx] = o;
}

// ====== fused QKV-GEMM + attention + PROJECTION (split-K atomics), per (b,h) ======
// 1024 thr / 16 waves. GEMM: in-stage fp32->bf16 A with 2 reg sets (load 2 ahead).
// Wp slice rows 0..255 staged into KL right after QK^T (hides under PV);
// rows 256..383 + O-tile land in EL after PV. Proj in 2 n-halves; atomicAdd to out.
__global__ __launch_bounds__(1024, 1)
void qkv_attn(const float* __restrict__ x, const unsigned short* __restrict__ Wt,
              const float* __restrict__ bias, float* __restrict__ out)
{
  __shared__ __align__(16) char EL[73728];   // A0+B0; Qtmp; E; then O(32K)+WpB(16K)
  __shared__ __align__(16) char KL[32768];   // A1; K; then Wp rows 0..255
  __shared__ __align__(16) char VL[32768];   // B1; V^T [64][256]
  __shared__ float Lpart[16][256];
  __shared__ float invL[256];

  const int bhRaw = blockIdx.x, tid = (int)threadIdx.x;
  const int bh = (bhRaw & 7) * 96 + (bhRaw >> 3);   // 768 = 8*96: bijective XCD swizzle
  const int w = tid >> 6, lane = tid & 63;
  const int la = lane & 15, kh = lane >> 4;
  const int b = bh / 6, h = bh - b * 6;
  const float* xf = x + (size_t)b * 256 * 384;
  const unsigned short* Wb = Wt + (size_t)h * 192 * 384;
  const unsigned short* Wpj = Wt + (size_t)1152 * 384;   // proj^T [384][384]
  char* A0 = EL;            // 32 KB
  char* B0 = EL + 32768;    // 24 KB
  char* A1 = KL;            // 32 KB (scratch during GEMM)
  char* B1 = VL;            // 24 KB of 32 KB (scratch during GEMM)

  // ---------------- QKV GEMM: wave tile 64 x 48, double-buffered ----------------
  const int wr = (w >> 2) * 64, wc = (w & 3) * 48;
  f32x4 acc[4][3];
  #pragma unroll
  for (int i = 0; i < 4; ++i)
    #pragma unroll
    for (int j = 0; j < 3; ++j) acc[i][j] = f32x4{0.f, 0.f, 0.f, 0.f};

  const int arow = tid >> 2, aqq = tid & 3;
  const float4* xfr = (const float4*)(xf + (size_t)arow * 384);

  float4 raA[4], raB[4];
  auto loadA = [&](float4 (&ra)[4], int kt) {
    const int base = kt * 16;
    #pragma unroll
    for (int i = 0; i < 2; ++i) {
      const int ch = aqq + 4 * i;
      ra[2*i]   = xfr[base + ch * 2];
      ra[2*i+1] = xfr[base + ch * 2 + 1];
    }
  };
  auto writeA = [&](char* A, const float4 (&ra)[4]) {
    #pragma unroll
    for (int i = 0; i < 2; ++i) {
      const int ch = aqq + 4 * i;
      float4 va = ra[2*i], vb = ra[2*i+1];
      short8 o;
      o[0] = (short)f2bf(va.x); o[1] = (short)f2bf(va.y);
      o[2] = (short)f2bf(va.z); o[3] = (short)f2bf(va.w);
      o[4] = (short)f2bf(vb.x); o[5] = (short)f2bf(vb.y);
      o[6] = (short)f2bf(vb.z); o[7] = (short)f2bf(vb.w);
      *(short8*)(A + arow * 128 + ((ch ^ (arow & 7)) << 4)) = o;
    }
  };
  auto stageB = [&](char* B, int kt) {
    const int Lb0 = tid * 16;
    const int row0 = Lb0 >> 7;
    const int kcs0 = ((Lb0 >> 4) & 7) ^ (row0 & 7);
    gll16(Wb + (size_t)row0 * 384 + kt * 64 + kcs0 * 8, B + Lb0);
    if (tid < 512) {
      const int Lb = 16384 + tid * 16;
      const int row = Lb >> 7;
      const int kcs = ((Lb >> 4) & 7) ^ (row & 7);
      gll16(Wb + (size_t)row * 384 + kt * 64 + kcs * 8, B + Lb);
    }
  };

  auto compute = [&](const char* A, const char* B) {
    #pragma unroll
    for (int kk = 0; kk < 2; ++kk) {
      const int ch = kk * 4 + kh;
      short8 a[4], bfr[3];
      #pragma unroll
      for (int mi = 0; mi < 4; ++mi) {
        const int r = wr + mi * 16 + la;
        a[mi] = *(const short8*)(A + r * 128 + ((ch ^ (r & 7)) << 4));
      }
      #pragma unroll
      for (int ni = 0; ni < 3; ++ni) {
        const int rB = wc + ni * 16 + la;
        bfr[ni] = *(const short8*)(B + rB * 128 + ((ch ^ (rB & 7)) << 4));
      }
      __builtin_amdgcn_s_setprio(1);
      #pragma unroll
      for (int mi = 0; mi < 4; ++mi)
        #pragma unroll
        for (int ni = 0; ni < 3; ++ni)
          acc[mi][ni] = __builtin_amdgcn_mfma_f32_16x16x32_bf16(a[mi], bfr[ni], acc[mi][ni], 0, 0, 0);
      __builtin_amdgcn_s_setprio(0);
    }
  };

  loadA(raA, 0);
  loadA(raB, 1);
  stageB(B0, 0);
  writeA(A0, raA);
  __syncthreads();

  loadA(raA, 2); stageB(B1, 1); writeA(A1, raB); compute(A0, B0);
  __syncthreads();
  loadA(raB, 3); stageB(B0, 2); writeA(A0, raA); compute(A1, B1);
  __syncthreads();
  loadA(raA, 4); stageB(B1, 3); writeA(A1, raB); compute(A0, B0);
  __syncthreads();
  loadA(raB, 5); stageB(B0, 4); writeA(A0, raA); compute(A1, B1);
  __syncthreads();
  stageB(B1, 5); writeA(A1, raB); compute(A0, B0);
  __syncthreads();
  compute(A1, B1);
  __syncthreads();

  // ---- epilogue: Q -> Qtmp (EL), K -> KL, V^T -> VL ----
  #pragma unroll
  for (int mi = 0; mi < 4; ++mi) {
    #pragma unroll
    for (int ni = 0; ni < 3; ++ni) {
      const int col = wc + ni * 16 + la;
      const int tb = wr + mi * 16 + kh * 4;
      if (col < 64) {
        const int d = col;
        #pragma unroll
        for (int j = 0; j < 4; ++j) {
          const int t = tb + j;
          *(unsigned short*)(EL + t * 128 + (((d >> 3) ^ (t & 7)) << 4) + (d & 7) * 2)
              = f2bf(acc[mi][ni][j]);
        }
      } else if (col < 128) {
        const int d = col - 64;
        #pragma unroll
        for (int j = 0; j < 4; ++j) {
          const int t = tb + j;
          *(unsigned short*)(KL + t * 128 + (((d >> 3) ^ (t & 7)) << 4) + (d & 7) * 2)
              = f2bf(acc[mi][ni][j]);
        }
      } else {
        const int d = col - 128;
        u16x4 pk;
        #pragma unroll
        for (int j = 0; j < 4; ++j) pk[j] = f2bf(acc[mi][ni][j]);
        *(u16x4*)(VL + d * 512 + (((tb >> 3) ^ (d & 7)) << 4) + (tb & 7) * 2) = pk;
      }
    }
  }
  __syncthreads();

  // ---- hoist Q fragments for this wave's PAIR {p, 15-p}, p = w>>1 ----
  const int p = w >> 1;
  const int rts[2] = { p, 15 - p };
  short8 qa[2][2];
  #pragma unroll
  for (int ti = 0; ti < 2; ++ti)
    #pragma unroll
    for (int kk = 0; kk < 2; ++kk) {
      const int r = rts[ti] * 16 + la;
      const int ch = kk * 4 + kh;
      qa[ti][kk] = *(const short8*)(EL + r * 128 + ((ch ^ (r & 7)) << 4));
    }
  __syncthreads();   // EL now free for E strips

  int wps[2], eoffs[2];
  #pragma unroll
  for (int ti = 0; ti < 2; ++ti) {
    const int rt = rts[ti];
    wps[ti] = 32 * ((rt + 2) >> 1);
    const int S = (rt & 1) ? ((rt + 1) * (rt + 1) / 4) : (rt * (rt + 2) / 4);
    eoffs[ti] = 1024 * S;
  }

  #pragma unroll
  for (int i = 0; i < 4; ++i) Lpart[w][i * 64 + lane] = 0.f;

  // ---- QK^T + masked exp -> E strips; col sums fused via shfl ----
  #pragma unroll
  for (int ti = 0; ti < 2; ++ti) {
    const int rt = rts[ti], wp = wps[ti], stride = wp * 2;
    char* Ebase = EL + eoffs[ti];
    const int nns = wp >> 4;
    for (int ns = (w & 1); ns < nns; ns += 2) {
      f32x4 s4 = f32x4{0.f, 0.f, 0.f, 0.f};
      #pragma unroll
      for (int kk = 0; kk < 2; ++kk) {
        const int rB = ns * 16 + la, kc = kk * 4 + kh;
        short8 bf = *(const short8*)(KL + rB * 128 + ((kc ^ (rB & 7)) << 4));
        s4 = __builtin_amdgcn_mfma_f32_16x16x32_bf16(qa[ti][kk], bf, s4, 0, 0, 0);
      }
      const int c = ns * 16 + la, cc = c >> 3, co = (c & 7) * 2;
      float ps = 0.f;
      #pragma unroll
      for (int j = 0; j < 4; ++j) {
        const int r = kh * 4 + j;
        const int t = rt * 16 + r;
        const float e = (t >= c) ? __expf(s4[j] * SCALE) : 0.f;
        ps += e;
        *(unsigned short*)(Ebase + r * stride + ((cc ^ (r & 3)) << 4) + co) = f2bf(e);
      }
      ps += __shfl_xor(ps, 16);
      ps += __shfl_xor(ps, 32);
      if (kh == 0) Lpart[w][c] += ps;
    }
  }
  __syncthreads();   // all K reads done -> KL free

  // ---- stage Wp rows 0..255 into KL (lands under colsum/foldV/PV) ----
  #pragma unroll
  for (int i = 0; i < 2; ++i) {
    const int Lb = i * 16384 + tid * 16;
    const int row = Lb >> 7;
    const int kcs = ((Lb >> 4) & 7) ^ (row & 7);
    gll16(Wpj + (size_t)row * 384 + h * 64 + kcs * 8, KL + Lb);
  }

  if (tid < 256) {
    float Ls = 0.f;
    #pragma unroll
    for (int ww = 0; ww < 16; ++ww) Ls += Lpart[ww][tid];
    invL[tid] = 1.f / Ls;
  }
  __syncthreads();

  // ---- fold 1/L_s into V ----
  {
    const int d = tid >> 4, qq = tid & 15;
    #pragma unroll
    for (int i = 0; i < 2; ++i) {
      const int kcp = qq * 2 + i;
      char* pch = VL + d * 512 + kcp * 16;
      short8 v = *(short8*)pch;
      const int sb = (kcp ^ (d & 7)) * 8;
      short8 o;
      #pragma unroll
      for (int e = 0; e < 8; ++e)
        o[e] = (short)f2bf(bf2f((unsigned short)v[e]) * invL[sb + e]);
      *(short8*)pch = o;
    }
  }
  __syncthreads();

  // ---- O = E * V' (big tile to wave bigw, SIMD-balanced); keep in regs ----
  const int bigw = 2 * p + ((p >> 1) & 1);
  const int tio = (w == bigw) ? 1 : 0;
  const int rto = rts[tio];
  f32x4 oacc[4];
  #pragma unroll
  for (int nd = 0; nd < 4; ++nd) oacc[nd] = f32x4{0.f, 0.f, 0.f, 0.f};
  {
    const int wp = wps[tio], stride = wp * 2;
    const char* Ebase = EL + eoffs[tio];
    const int nks = wp >> 5;
    for (int ks = 0; ks < nks; ++ks) {
      const int cc = ks * 4 + kh;
      short8 ea = *(const short8*)(Ebase + la * stride + ((cc ^ (la & 3)) << 4));
      __builtin_amdgcn_s_setprio(1);
      #pragma unroll
      for (int nd = 0; nd < 4; ++nd) {
        const int d = nd * 16 + la;
        short8 vb = *(const short8*)(VL + d * 512 + ((cc ^ (d & 7)) << 4));
        oacc[nd] = __builtin_amdgcn_mfma_f32_16x16x32_bf16(ea, vb, oacc[nd], 0, 0, 0);
      }
      __builtin_amdgcn_s_setprio(0);
    }
  }
  __syncthreads();   // all E/V reads done -> EL free

  // ---- stage Wp rows 256..383 into EL+32K; write O tile into EL[0,32K) ----
  {
    const int Lb = tid * 16;             // 16 KB
    const int row = 256 + (Lb >> 7);
    const int kcs = ((Lb >> 4) & 7) ^ (row & 7);
    gll16(Wpj + (size_t)row * 384 + h * 64 + kcs * 8, EL + 32768 + Lb);
  }
  #pragma unroll
  for (int nd = 0; nd < 4; ++nd) {
    const int d = nd * 16 + la;
    #pragma unroll
    for (int j = 0; j < 4; ++j) {
      const int t = rto * 16 + kh * 4 + j;
      *(unsigned short*)(EL + t * 128 + (((d >> 3) ^ (t & 7)) << 4) + (d & 7) * 2)
          = f2bf(oacc[nd][j]);
    }
  }
  __syncthreads();

  // ---- projection: out[b,t,:] += O[256x64] * Wp_h[64x384] (+bias if h==0) ----
  float* outp = out + (size_t)b * 256 * 384;
  const int wr2 = (w >> 2) * 64, wc2 = (w & 3) * 96;
  #pragma unroll
  for (int nh = 0; nh < 2; ++nh) {
    f32x4 acc2[4][3];
    #pragma unroll
    for (int i = 0; i < 4; ++i)
      #pragma unroll
      for (int j = 0; j < 3; ++j) acc2[i][j] = f32x4{0.f, 0.f, 0.f, 0.f};
    #pragma unroll
    for (int kk = 0; kk < 2; ++kk) {
      const int ch = kk * 4 + kh;
      short8 a[4], bfr[3];
      #pragma unroll
      for (int mi = 0; mi < 4; ++mi) {
        const int r = wr2 + mi * 16 + la;
        a[mi] = *(const short8*)(EL + r * 128 + ((ch ^ (r & 7)) << 4));
      }
      #pragma unroll
      for (int ni = 0; ni < 3; ++ni) {
        const int rB = wc2 + nh * 48 + ni * 16 + la;
        const char* base = (rB < 256) ? (KL + rB * 128)
                                      : (EL + 32768 + (rB - 256) * 128);
        bfr[ni] = *(const short8*)(base + ((ch ^ (rB & 7)) << 4));
      }
      __builtin_amdgcn_s_setprio(1);
      #pragma unroll
      for (int mi = 0; mi < 4; ++mi)
        #pragma unroll
        for (int ni = 0; ni < 3; ++ni)
          acc2[mi][ni] = __builtin_amdgcn_mfma_f32_16x16x32_bf16(a[mi], bfr[ni], acc2[mi][ni], 0, 0, 0);
      __builtin_amdgcn_s_setprio(0);
    }
    #pragma unroll
    for (int ni = 0; ni < 3; ++ni) {
      const int nl = wc2 + nh * 48 + ni * 16 + la;
      const float bn = (h == 0) ? bias[nl] : 0.f;
      #pragma unroll
      for (int mi = 0; mi < 4; ++mi) {
        #pragma unroll
        for (int j = 0; j < 4; ++j) {
          const int t = wr2 + mi * 16 + kh * 4 + j;
          atomicAdd(&outp[(size_t)t * 384 + nl], acc2[mi][ni][j] + bn);
        }
      }
    }
  }
}

// ================= fallback (fp32) for small ws =================
__global__ __launch_bounds__(256, 1)
void mha_fused(const float* __restrict__ x, const float* __restrict__ Wq,
               const float* __restrict__ Wk, const float* __restrict__ Wv,
               const float* __restrict__ Wp, const float* __restrict__ bp,
               float* __restrict__ out)
{
  const int bh = blockIdx.x;
  const int b = bh / HEADS, h = bh % HEADS;
  const int tid = (int)threadIdx.x;
  const int wave = tid >> 6, lane = tid & 63;
  const float* xb = x + (size_t)b * TT * EMB;
  const float* wq = Wq + (size_t)h * EMB * DH;
  const float* wk = Wk + (size_t)h * EMB * DH;
  const float* wv = Wv + (size_t)h * EMB * DH;
  __shared__ float Ks[TT][68];
  __shared__ float Vs[TT][64];
  __shared__ float Qt[64][68];
  for (int c = 0; c < 4; ++c) {
    const int s0 = wave * 64 + c * 16;
    float ak[16], av[16];
    #pragma unroll
    for (int r = 0; r < 16; ++r) { ak[r] = 0.f; av[r] = 0.f; }
    for (int e = 0; e < EMB; ++e) {
      const float kk = wk[e * DH + lane];
      const float vv = wv[e * DH + lane];
      #pragma unroll
      for (int r = 0; r < 16; ++r) {
        const float xv = xb[(s0 + r) * EMB + e];
        ak[r] += xv * kk; av[r] += xv * vv;
      }
    }
    #pragma unroll
    for (int r = 0; r < 16; ++r) { Ks[s0 + r][lane] = ak[r]; Vs[s0 + r][lane] = av[r]; }
  }
  __syncthreads();
  const int s = tid;
  float kreg[64];
  {
    const float4* k4 = (const float4*)&Ks[s][0];
    #pragma unroll
    for (int i = 0; i < 16; ++i) {
      float4 kv = k4[i];
      kreg[4*i+0] = kv.x; kreg[4*i+1] = kv.y; kreg[4*i+2] = kv.z; kreg[4*i+3] = kv.w;
    }
  }
  float Lsum = 0.f;
  for (int tile = 0; tile < 4; ++tile) {
    {
      const int r0 = tile * 64 + wave * 16;
      float aq[16];
      #pragma unroll
      for (int r = 0; r < 16; ++r) aq[r] = 0.f;
      for (int e = 0; e < EMB; ++e) {
        const float qw = wq[e * DH + lane];
        #pragma unroll
        for (int r = 0; r < 16; ++r) aq[r] += xb[(r0 + r) * EMB + e] * qw;
      }
      __syncthreads();
      #pragma unroll
      for (int r = 0; r < 16; ++r) Qt[wave*16 + r][lane] = aq[r];
      __syncthreads();
    }
    const int tbase = tile * 64;
    if (tbase + 63 >= s) {
      for (int tr = 0; tr < 64; ++tr) {
        const int t = tbase + tr;
        if (t < s) continue;
        float w = 0.f;
        const float4* q4 = (const float4*)&Qt[tr][0];
        #pragma unroll
        for (int i = 0; i < 16; ++i) {
          float4 qv = q4[i];
          w += qv.x*kreg[4*i+0] + qv.y*kreg[4*i+1] + qv.z*kreg[4*i+2] + qv.w*kreg[4*i+3];
        }
        Lsum += __expf(w * SCALE);
      }
    }
  }
  __syncthreads();
  {
    const float invL = 1.0f / Lsum;
    float4* v4 = (float4*)&Vs[s][0];
    #pragma unroll
    for (int i = 0; i < 16; ++i) {
      float4 vv = v4[i];
      vv.x *= invL; vv.y *= invL; vv.z *= invL; vv.w *= invL;
      v4[i] = vv;
    }
  }
  __syncthreads();
  const float bias1 = bp[tid];
  const float bias2 = (tid < 128) ? bp[256 + tid] : 0.f;
  const int tr = tid >> 2, dq = tid & 3;
  float* ob = out + (size_t)b * TT * EMB;
  for (int tile = 0; tile < 4; ++tile) {
    {
      const int r0 = tile * 64 + wave * 16;
      float aq[16];
      #pragma unroll
      for (int r = 0; r < 16; ++r) aq[r] = 0.f;
      for (int e = 0; e < EMB; ++e) {
        const float qw = wq[e * DH + lane];
        #pragma unroll
        for (int r = 0; r < 16; ++r) aq[r] += xb[(r0 + r) * EMB + e] * qw;
      }
      __syncthreads();
      #pragma unroll
      for (int r = 0; r < 16; ++r) Qt[wave*16 + r][lane] = aq[r];
      __syncthreads();
    }
    const int t = tile * 64 + tr;
    float qreg[16];
    {
      const float4* q4 = (const float4*)&Qt[tr][dq * 16];
      #pragma unroll
      for (int i = 0; i < 4; ++i) {
        float4 qv = q4[i];
        qreg[4*i+0] = qv.x; qreg[4*i+1] = qv.y; qreg[4*i+2] = qv.z; qreg[4*i+3] = qv.w;
      }
    }
    float acc[16];
    #pragma unroll
    for (int i = 0; i < 16; ++i) acc[i] = 0.f;
    for (int s2 = 0; s2 <= t; ++s2) {
      const float4* kk4 = (const float4*)&Ks[s2][dq * 16];
      float part = 0.f;
      #pragma unroll
      for (int i = 0; i < 4; ++i) {
        float4 kv = kk4[i];
        part += qreg[4*i+0]*kv.x + qreg[4*i+1]*kv.y + qreg[4*i+2]*kv.z + qreg[4*i+3]*kv.w;
      }
      part += __shfl_xor(part, 1);
      part += __shfl_xor(part, 2);
      const float p = __expf(part * SCALE);
      const float4* vv4 = (const float4*)&Vs[s2][dq * 16];
      #pragma unroll
      for (int i = 0; i < 4; ++i) {
        float4 vv = vv4[i];
        acc[4*i+0] += p * vv.x; acc[4*i+1] += p * vv.y;
        acc[4*i+2] += p * vv.z; acc[4*i+3] += p * vv.w;
      }
    }
    __syncthreads();
    #pragma unroll
    for (int i = 0; i < 16; ++i) Qt[tr][dq*16 + i] = acc[i];
    __syncthreads();
    const int c1 = tid;
    const int c2 = 256 + tid;
    for (int rg = 0; rg < 4; ++rg) {
      float a1[16], a2[16];
      #pragma unroll
      for (int r = 0; r < 16; ++r) { a1[r] = 0.f; a2[r] = 0.f; }
      for (int d = 0; d < 64; ++d) {
        const float wp1 = Wp[(size_t)(h*64 + d) * EMB + c1];
        const float wp2 = (tid < 128) ? Wp[(size_t)(h*64 + d) * EMB + c2] : 0.f;
        #pragma unroll
        for (int r = 0; r < 16; ++r) {
          const float a = Qt[rg*16 + r][d];
          a1[r] += a * wp1; a2[r] += a * wp2;
        }
      }
      if (h == 0) {
        #pragma unroll
        for (int r = 0; r < 16; ++r) { a1[r] += bias1; a2[r] += bias2; }
      }
      const int trow0 = tile*64 + rg*16;
      #pragma unroll
      for (int r = 0; r < 16; ++r)
        atomicAdd(&ob[(size_t)(trow0 + r) * EMB + c1], a1[r]);
      if (tid < 128) {
        #pragma unroll
        for (int r = 0; r < 16; ++r)
          atomicAdd(&ob[(size_t)(trow0 + r) * EMB + c2], a2[r]);
      }
    }
    __syncthreads();
  }
}

extern "C" void kernel_launch(void* const* d_in, const int* in_sizes, int n_in,
                              void* d_out, int out_size, void* d_ws, size_t ws_size,
                              hipStream_t stream) {
  const float* x  = (const float*)d_in[0];
  const float* Wq = (const float*)d_in[1];
  const float* Wk = (const float*)d_in[2];
  const float* Wv = (const float*)d_in[3];
  const float* Wp = (const float*)d_in[4];
  const float* bp = (const float*)d_in[5];

  const int nb = in_sizes[0] / (TT * EMB);       // batch (128)
  const size_t WT = (size_t)1536 * 384 * 2;

  if (ws_size < WT || nb * HEADS != 768) {
    hipMemsetAsync(d_out, 0, (size_t)out_size * sizeof(float), stream);
    mha_fused<<<nb * HEADS, 256, 0, stream>>>(x, Wq, Wk, Wv, Wp, bp, (float*)d_out);
    return;
  }

  unsigned short* Wt = (unsigned short*)d_ws;

  hipMemsetAsync(d_out, 0, (size_t)out_size * sizeof(float), stream);
  build_wt<<<288, 256, 0, stream>>>(Wq, Wk, Wv, Wp, Wt);

  qkv_attn<<<nb * HEADS, 1024, 0, stream>>>(x, Wt, bp, (float*)d_out);
}

// Round 17
// 100.840 us; speedup vs baseline: 2.9210x; 2.9210x over previous
//
#include <hip/hip_runtime.h>

#define EMB 384
#define HEADS 6
#define DH 64
#define TT 256

constexpr float SCALE = 0.05103103630798288f;  // 384^-0.5

typedef __attribute__((ext_vector_type(8))) short short8;
typedef __attribute__((ext_vector_type(4))) float f32x4;
typedef __attribute__((ext_vector_type(4))) unsigned short u16x4;

__device__ __forceinline__ unsigned short f2bf(float f) {
  unsigned int u = __builtin_bit_cast(unsigned int, f);
  u += 0x7FFFu + ((u >> 16) & 1u);   // RNE
  return (unsigned short)(u >> 16);
}
__device__ __forceinline__ float bf2f(unsigned short u) {
  unsigned int v = ((unsigned int)u) << 16;
  return __builtin_bit_cast(float, v);
}
__device__ __forceinline__ void gll16(const void* g, void* l) {
  __builtin_amdgcn_global_load_lds(
      (const __attribute__((address_space(1))) unsigned int*)g,
      (__attribute__((address_space(3))) unsigned int*)l, 16, 0, 0);
}

// ---- K0: build Wt[1536][384] bf16. Rows 0..1151: per-HEAD blocks of 192
// (q d0-63 | k d0-63 | v d0-63); rows 1152..1535: proj^T. ----
__global__ __launch_bounds__(256)
void build_wt(const float* __restrict__ Wq, const float* __restrict__ Wk,
              const float* __restrict__ Wv, const float* __restrict__ Wp,
              unsigned short* __restrict__ Wt) {
  int idx = blockIdx.x * 256 + threadIdx.x;  // 1536*48 = 73728
  int n = idx / 48, e0 = (idx % 48) * 8;
  const float* src; int stride;
  if (n < 1152) {
    int h = n / 192, rem = n % 192, qkv = rem >> 6, d = rem & 63;
    const float* W = (qkv == 0) ? Wq : (qkv == 1) ? Wk : Wv;
    src = W + ((size_t)h * EMB + e0) * DH + d; stride = DH;
  } else {
    int c = n - 1152;
    src = Wp + (size_t)e0 * EMB + c; stride = EMB;
  }
  short8 o;
  #pragma unroll
  for (int j = 0; j < 8; ++j) o[j] = (short)f2bf(src[j * stride]);
  ((short8*)Wt)[idx] = o;
}

// ================= fused QKV-GEMM + attention, one block per (b,h) =================
// 1024 thr / 16 waves. A = x fp32 converted in-stage with TWO reg sets:
// step k issues loadA(k+2), writes the set loaded at k-1 (landed -> no wait),
// then computes. B via gll16 double-buffer. XCD swizzle for x L2/L3 locality.
__global__ __launch_bounds__(1024, 1)
void qkv_attn(const float* __restrict__ x, const unsigned short* __restrict__ Wt,
              unsigned short* __restrict__ O)
{
  __shared__ __align__(16) char EL[73728];   // GEMM buf0: A0(32K)+B0(24K); then Qtmp; then E
  __shared__ __align__(16) char KL[32768];   // GEMM buf1 A1; then K [256][64] swizzled
  __shared__ __align__(16) char VL[32768];   // GEMM buf1 B1 (24K); then V^T [64][256] swizzled
  __shared__ float Lpart[16][256];
  __shared__ float invL[256];

  const int bhRaw = blockIdx.x, tid = (int)threadIdx.x;
  const int bh = (bhRaw & 7) * 96 + (bhRaw >> 3);   // 768 = 8*96: bijective XCD swizzle
  const int w = tid >> 6, lane = tid & 63;
  const int la = lane & 15, kh = lane >> 4;
  const int b = bh / 6, h = bh - b * 6;
  const float* xf = x + (size_t)b * 256 * 384;
  const unsigned short* Wb = Wt + (size_t)h * 192 * 384;
  char* A0 = EL;            // 32 KB
  char* B0 = EL + 32768;    // 24 KB
  char* A1 = KL;            // 32 KB (scratch during GEMM)
  char* B1 = VL;            // 24 KB of 32 KB (scratch during GEMM)

  // ---------------- QKV GEMM: wave tile 64 x 48, double-buffered ----------------
  const int wr = (w >> 2) * 64, wc = (w & 3) * 48;
  f32x4 acc[4][3];
  #pragma unroll
  for (int i = 0; i < 4; ++i)
    #pragma unroll
    for (int j = 0; j < 3; ++j) acc[i][j] = f32x4{0.f, 0.f, 0.f, 0.f};

  // A reg-staging: 4 threads/row, thread covers chunks {aqq, aqq+4} (8 fp32 each)
  const int arow = tid >> 2, aqq = tid & 3;
  const float4* xfr = (const float4*)(xf + (size_t)arow * 384);

  float4 raA[4], raB[4];
  auto loadA = [&](float4 (&ra)[4], int kt) {
    const int base = kt * 16;              // float4 units (64 floats / step)
    #pragma unroll
    for (int i = 0; i < 2; ++i) {
      const int ch = aqq + 4 * i;
      ra[2*i]   = xfr[base + ch * 2];
      ra[2*i+1] = xfr[base + ch * 2 + 1];
    }
  };
  auto writeA = [&](char* A, const float4 (&ra)[4]) {
    #pragma unroll
    for (int i = 0; i < 2; ++i) {
      const int ch = aqq + 4 * i;
      float4 va = ra[2*i], vb = ra[2*i+1];
      short8 o;
      o[0] = (short)f2bf(va.x); o[1] = (short)f2bf(va.y);
      o[2] = (short)f2bf(va.z); o[3] = (short)f2bf(va.w);
      o[4] = (short)f2bf(vb.x); o[5] = (short)f2bf(vb.y);
      o[6] = (short)f2bf(vb.z); o[7] = (short)f2bf(vb.w);
      *(short8*)(A + arow * 128 + ((ch ^ (arow & 7)) << 4)) = o;
    }
  };
  auto stageB = [&](char* B, int kt) {     // gll16, [192][64] bf16, 24KB
    const int Lb0 = tid * 16;
    const int row0 = Lb0 >> 7;
    const int kcs0 = ((Lb0 >> 4) & 7) ^ (row0 & 7);
    gll16(Wb + (size_t)row0 * 384 + kt * 64 + kcs0 * 8, B + Lb0);
    if (tid < 512) {
      const int Lb = 16384 + tid * 16;
      const int row = Lb >> 7;
      const int kcs = ((Lb >> 4) & 7) ^ (row & 7);
      gll16(Wb + (size_t)row * 384 + kt * 64 + kcs * 8, B + Lb);
    }
  };

  auto compute = [&](const char* A, const char* B) {
    #pragma unroll
    for (int kk = 0; kk < 2; ++kk) {
      const int ch = kk * 4 + kh;
      short8 a[4], bfr[3];
      #pragma unroll
      for (int mi = 0; mi < 4; ++mi) {
        const int r = wr + mi * 16 + la;
        a[mi] = *(const short8*)(A + r * 128 + ((ch ^ (r & 7)) << 4));
      }
      #pragma unroll
      for (int ni = 0; ni < 3; ++ni) {
        const int rB = wc + ni * 16 + la;
        bfr[ni] = *(const short8*)(B + rB * 128 + ((ch ^ (rB & 7)) << 4));
      }
      __builtin_amdgcn_s_setprio(1);
      #pragma unroll
      for (int mi = 0; mi < 4; ++mi)
        #pragma unroll
        for (int ni = 0; ni < 3; ++ni)
          acc[mi][ni] = __builtin_amdgcn_mfma_f32_16x16x32_bf16(a[mi], bfr[ni], acc[mi][ni], 0, 0, 0);
      __builtin_amdgcn_s_setprio(0);
    }
  };

  // prologue: raA=x(0) (cold wait in writeA), raB=x(1) in flight
  loadA(raA, 0);
  loadA(raB, 1);
  stageB(B0, 0);
  writeA(A0, raA);
  __syncthreads();                       // A0+B0 ready

  // step 0: compute k=0; write x(1); load x(2)
  loadA(raA, 2); stageB(B1, 1); writeA(A1, raB); compute(A0, B0);
  __syncthreads();
  // step 1: compute k=1; write x(2); load x(3)
  loadA(raB, 3); stageB(B0, 2); writeA(A0, raA); compute(A1, B1);
  __syncthreads();
  // step 2
  loadA(raA, 4); stageB(B1, 3); writeA(A1, raB); compute(A0, B0);
  __syncthreads();
  // step 3
  loadA(raB, 5); stageB(B0, 4); writeA(A0, raA); compute(A1, B1);
  __syncthreads();
  // step 4
  stageB(B1, 5); writeA(A1, raB); compute(A0, B0);
  __syncthreads();
  // step 5
  compute(A1, B1);
  __syncthreads();   // all reads of A1/B1 done before epilogue overwrites KL/VL

  // ---- epilogue: Q -> Qtmp (EL, [256][64] swizzled), K -> KL, V^T -> VL ----
  #pragma unroll
  for (int mi = 0; mi < 4; ++mi) {
    #pragma unroll
    for (int ni = 0; ni < 3; ++ni) {
      const int col = wc + ni * 16 + la;
      const int tb = wr + mi * 16 + kh * 4;
      if (col < 64) {
        const int d = col;
        #pragma unroll
        for (int j = 0; j < 4; ++j) {
          const int t = tb + j;
          *(unsigned short*)(EL + t * 128 + (((d >> 3) ^ (t & 7)) << 4) + (d & 7) * 2)
              = f2bf(acc[mi][ni][j]);
        }
      } else if (col < 128) {
        const int d = col - 64;
        #pragma unroll
        for (int j = 0; j < 4; ++j) {
          const int t = tb + j;
          *(unsigned short*)(KL + t * 128 + (((d >> 3) ^ (t & 7)) << 4) + (d & 7) * 2)
              = f2bf(acc[mi][ni][j]);
        }
      } else {
        const int d = col - 128;
        u16x4 pk;
        #pragma unroll
        for (int j = 0; j < 4; ++j) pk[j] = f2bf(acc[mi][ni][j]);
        *(u16x4*)(VL + d * 512 + (((tb >> 3) ^ (d & 7)) << 4) + (tb & 7) * 2) = pk;
      }
    }
  }
  __syncthreads();

  // ---- hoist Q fragments for this wave's PAIR {p, 15-p}, p = w>>1 ----
  const int p = w >> 1;
  const int rts[2] = { p, 15 - p };
  short8 qa[2][2];
  #pragma unroll
  for (int ti = 0; ti < 2; ++ti)
    #pragma unroll
    for (int kk = 0; kk < 2; ++kk) {
      const int r = rts[ti] * 16 + la;
      const int ch = kk * 4 + kh;
      qa[ti][kk] = *(const short8*)(EL + r * 128 + ((ch ^ (r & 7)) << 4));
    }
  __syncthreads();   // EL now free for E strips

  int wps[2], eoffs[2];
  #pragma unroll
  for (int ti = 0; ti < 2; ++ti) {
    const int rt = rts[ti];
    wps[ti] = 32 * ((rt + 2) >> 1);
    const int S = (rt & 1) ? ((rt + 1) * (rt + 1) / 4) : (rt * (rt + 2) / 4);
    eoffs[ti] = 1024 * S;
  }

  // ---- zero own Lpart row (wave-local) ----
  #pragma unroll
  for (int i = 0; i < 4; ++i) Lpart[w][i * 64 + lane] = 0.f;

  // ---- QK^T + masked exp -> E strips; ns-parity split across the pair's waves ----
  #pragma unroll
  for (int ti = 0; ti < 2; ++ti) {
    const int rt = rts[ti], wp = wps[ti], stride = wp * 2;
    char* Ebase = EL + eoffs[ti];
    const int nns = wp >> 4;
    for (int ns = (w & 1); ns < nns; ns += 2) {
      f32x4 s4 = f32x4{0.f, 0.f, 0.f, 0.f};
      #pragma unroll
      for (int kk = 0; kk < 2; ++kk) {
        const int rB = ns * 16 + la, kc = kk * 4 + kh;
        short8 bf = *(const short8*)(KL + rB * 128 + ((kc ^ (rB & 7)) << 4));
        s4 = __builtin_amdgcn_mfma_f32_16x16x32_bf16(qa[ti][kk], bf, s4, 0, 0, 0);
      }
      const int c = ns * 16 + la, cc = c >> 3, co = (c & 7) * 2;
      float ps = 0.f;
      #pragma unroll
      for (int j = 0; j < 4; ++j) {
        const int r = kh * 4 + j;
        const int t = rt * 16 + r;
        const float e = (t >= c) ? __expf(s4[j] * SCALE) : 0.f;
        ps += e;
        *(unsigned short*)(Ebase + r * stride + ((cc ^ (r & 3)) << 4) + co) = f2bf(e);
      }
      ps += __shfl_xor(ps, 16);
      ps += __shfl_xor(ps, 32);        // 16-row tile-column sum in all kh lanes
      if (kh == 0) Lpart[w][c] += ps;  // wave-local row: no race
    }
  }
  __syncthreads();

  if (tid < 256) {
    float Ls = 0.f;
    #pragma unroll
    for (int ww = 0; ww < 16; ++ww) Ls += Lpart[ww][tid];
    invL[tid] = 1.f / Ls;
  }
  __syncthreads();

  // ---- fold 1/L_s into V (1024 threads: 2 chunks each) ----
  {
    const int d = tid >> 4, qq = tid & 15;
    #pragma unroll
    for (int i = 0; i < 2; ++i) {
      const int kcp = qq * 2 + i;
      char* pch = VL + d * 512 + kcp * 16;
      short8 v = *(short8*)pch;
      const int sb = (kcp ^ (d & 7)) * 8;
      short8 o;
      #pragma unroll
      for (int e = 0; e < 8; ++e)
        o[e] = (short)f2bf(bf2f((unsigned short)v[e]) * invL[sb + e]);
      *(short8*)pch = o;
    }
  }
  __syncthreads();

  // ---- O = E * V': big tile to wave bigw = 2p + ((p>>1)&1) (SIMD-balanced) ----
  unsigned short* Og = O + (size_t)b * 256 * 384 + h * 64;
  {
    const int bigw = 2 * p + ((p >> 1) & 1);
    const int ti = (w == bigw) ? 1 : 0;
    const int rt = rts[ti], wp = wps[ti], stride = wp * 2;
    const char* Ebase = EL + eoffs[ti];
    f32x4 oacc[4];
    #pragma unroll
    for (int nd = 0; nd < 4; ++nd) oacc[nd] = f32x4{0.f, 0.f, 0.f, 0.f};
    const int nks = wp >> 5;
    for (int ks = 0; ks < nks; ++ks) {
      const int cc = ks * 4 + kh;
      short8 ea = *(const short8*)(Ebase + la * stride + ((cc ^ (la & 3)) << 4));
      __builtin_amdgcn_s_setprio(1);
      #pragma unroll
      for (int nd = 0; nd < 4; ++nd) {
        const int d = nd * 16 + la;
        short8 vb = *(const short8*)(VL + d * 512 + ((cc ^ (d & 7)) << 4));
        oacc[nd] = __builtin_amdgcn_mfma_f32_16x16x32_bf16(ea, vb, oacc[nd], 0, 0, 0);
      }
      __builtin_amdgcn_s_setprio(0);
    }
    #pragma unroll
    for (int nd = 0; nd < 4; ++nd) {
      const int d = nd * 16 + la;
      #pragma unroll
      for (int j = 0; j < 4; ++j) {
        const int t = rt * 16 + kh * 4 + j;
        Og[(size_t)t * 384 + d] = f2bf(oacc[nd][j]);
      }
    }
  }
}

// ---------------- proj GEMM: out = O * proj + bias (XCD-swizzled) ----------------
__global__ __launch_bounds__(512, 1)
void proj_gemm(const unsigned short* __restrict__ A, const unsigned short* __restrict__ Bt,
               float* __restrict__ Co, const float* __restrict__ bias)
{
  __shared__ __align__(16) unsigned short AL[128 * 384];    // 96 KB
  __shared__ __align__(16) unsigned short BL[2][128 * 64];  // 2 x 16 KB
  const int tid = (int)threadIdx.x, w = tid >> 6, lane = tid & 63;
  const int la = lane & 15, kh = lane >> 4;
  // 256 = 8*32 bijective swizzle: same-XCD as the qkv blocks that wrote these rows
  const int mt = ((int)blockIdx.x & 7) * 32 + ((int)blockIdx.x >> 3);
  const int m0 = mt * 128;

  {
    const int row = tid >> 2, qq = tid & 3;
    const short8* O8 = (const short8*)(A + (size_t)(m0 + row) * 384);
    #pragma unroll
    for (int i = 0; i < 12; ++i) {
      const int ch = qq + 4 * i;
      *(short8*)((char*)AL + row * 768 + ((ch ^ (row & 7)) << 4)) = O8[ch];
    }
  }

  auto stageB = [&](int buf, int n0, int k0) {
    #pragma unroll
    for (int i = 0; i < 2; ++i) {
      const int Lb = i * 8192 + tid * 16;
      const int row = Lb >> 7;
      const int kcs = ((Lb >> 4) & 7) ^ (row & 7);
      gll16(Bt + (size_t)(n0 + row) * 384 + k0 + kcs * 8, (char*)BL[buf] + Lb);
    }
  };

  stageB(0, 0, 0);
  __syncthreads();

  const int wr = (w >> 2) * 64, wc = (w & 3) * 32;
  int buf = 0;
  for (int nt = 0; nt < 3; ++nt) {
    f32x4 acc[4][2];
    #pragma unroll
    for (int i = 0; i < 4; ++i) { acc[i][0] = f32x4{0.f,0.f,0.f,0.f}; acc[i][1] = f32x4{0.f,0.f,0.f,0.f}; }

    for (int kt = 0; kt < 6; ++kt) {
      if (kt < 5)          stageB(buf ^ 1, nt * 128, (kt + 1) * 64);
      else if (nt + 1 < 3) stageB(buf ^ 1, (nt + 1) * 128, 0);
      #pragma unroll
      for (int kk = 0; kk < 2; ++kk) {
        short8 a[4], bb[2];
        const int chA = kt * 8 + kk * 4 + kh;
        #pragma unroll
        for (int mi = 0; mi < 4; ++mi) {
          const int r = wr + mi * 16 + la;
          a[mi] = *(const short8*)((const char*)AL + r * 768 + ((chA ^ (r & 7)) << 4));
        }
        const int chB = kk * 4 + kh;
        #pragma unroll
        for (int ni = 0; ni < 2; ++ni) {
          const int rB = wc + ni * 16 + la;
          bb[ni] = *(const short8*)((const char*)BL[buf] + rB * 128 + ((chB ^ (rB & 7)) << 4));
        }
        __builtin_amdgcn_s_setprio(1);
        #pragma unroll
        for (int mi = 0; mi < 4; ++mi)
          #pragma unroll
          for (int ni = 0; ni < 2; ++ni)
            acc[mi][ni] = __builtin_amdgcn_mfma_f32_16x16x32_bf16(a[mi], bb[ni], acc[mi][ni], 0, 0, 0);
        __builtin_amdgcn_s_setprio(0);
      }
      __syncthreads();
      buf ^= 1;
    }

    #pragma unroll
    for (int mi = 0; mi < 4; ++mi) {
      const int mbase = m0 + wr + mi * 16 + kh * 4;
      #pragma unroll
      for (int ni = 0; ni < 2; ++ni) {
        const int nl = nt * 128 + wc + ni * 16 + la;
        const float bn = bias[nl];
        #pragma unroll
        for (int j = 0; j < 4; ++j)
          Co[(size_t)(mbase + j) * 384 + nl] = acc[mi][ni][j] + bn;
      }
    }
  }
}

// ================= fallback (fp32) for small ws =================
__global__ __launch_bounds__(256, 1)
void mha_fused(const float* __restrict__ x, const float* __restrict__ Wq,
               const float* __restrict__ Wk, const float* __restrict__ Wv,
               const float* __restrict__ Wp, const float* __restrict__ bp,
               float* __restrict__ out)
{
  const int bh = blockIdx.x;
  const int b = bh / HEADS, h = bh % HEADS;
  const int tid = (int)threadIdx.x;
  const int wave = tid >> 6, lane = tid & 63;
  const float* xb = x + (size_t)b * TT * EMB;
  const float* wq = Wq + (size_t)h * EMB * DH;
  const float* wk = Wk + (size_t)h * EMB * DH;
  const float* wv = Wv + (size_t)h * EMB * DH;
  __shared__ float Ks[TT][68];
  __shared__ float Vs[TT][64];
  __shared__ float Qt[64][68];
  for (int c = 0; c < 4; ++c) {
    const int s0 = wave * 64 + c * 16;
    float ak[16], av[16];
    #pragma unroll
    for (int r = 0; r < 16; ++r) { ak[r] = 0.f; av[r] = 0.f; }
    for (int e = 0; e < EMB; ++e) {
      const float kk = wk[e * DH + lane];
      const float vv = wv[e * DH + lane];
      #pragma unroll
      for (int r = 0; r < 16; ++r) {
        const float xv = xb[(s0 + r) * EMB + e];
        ak[r] += xv * kk; av[r] += xv * vv;
      }
    }
    #pragma unroll
    for (int r = 0; r < 16; ++r) { Ks[s0 + r][lane] = ak[r]; Vs[s0 + r][lane] = av[r]; }
  }
  __syncthreads();
  const int s = tid;
  float kreg[64];
  {
    const float4* k4 = (const float4*)&Ks[s][0];
    #pragma unroll
    for (int i = 0; i < 16; ++i) {
      float4 kv = k4[i];
      kreg[4*i+0] = kv.x; kreg[4*i+1] = kv.y; kreg[4*i+2] = kv.z; kreg[4*i+3] = kv.w;
    }
  }
  float Lsum = 0.f;
  for (int tile = 0; tile < 4; ++tile) {
    {
      const int r0 = tile * 64 + wave * 16;
      float aq[16];
      #pragma unroll
      for (int r = 0; r < 16; ++r) aq[r] = 0.f;
      for (int e = 0; e < EMB; ++e) {
        const float qw = wq[e * DH + lane];
        #pragma unroll
        for (int r = 0; r < 16; ++r) aq[r] += xb[(r0 + r) * EMB + e] * qw;
      }
      __syncthreads();
      #pragma unroll
      for (int r = 0; r < 16; ++r) Qt[wave*16 + r][lane] = aq[r];
      __syncthreads();
    }
    const int tbase = tile * 64;
    if (tbase + 63 >= s) {
      for (int tr = 0; tr < 64; ++tr) {
        const int t = tbase + tr;
        if (t < s) continue;
        float w = 0.f;
        const float4* q4 = (const float4*)&Qt[tr][0];
        #pragma unroll
        for (int i = 0; i < 16; ++i) {
          float4 qv = q4[i];
          w += qv.x*kreg[4*i+0] + qv.y*kreg[4*i+1] + qv.z*kreg[4*i+2] + qv.w*kreg[4*i+3];
        }
        Lsum += __expf(w * SCALE);
      }
    }
  }
  __syncthreads();
  {
    const float invL = 1.0f / Lsum;
    float4* v4 = (float4*)&Vs[s][0];
    #pragma unroll
    for (int i = 0; i < 16; ++i) {
      float4 vv = v4[i];
      vv.x *= invL; vv.y *= invL; vv.z *= invL; vv.w *= invL;
      v4[i] = vv;
    }
  }
  __syncthreads();
  const float bias1 = bp[tid];
  const float bias2 = (tid < 128) ? bp[256 + tid] : 0.f;
  const int tr = tid >> 2, dq = tid & 3;
  float* ob = out + (size_t)b * TT * EMB;
  for (int tile = 0; tile < 4; ++tile) {
    {
      const int r0 = tile * 64 + wave * 16;
      float aq[16];
      #pragma unroll
      for (int r = 0; r < 16; ++r) aq[r] = 0.f;
      for (int e = 0; e < EMB; ++e) {
        const float qw = wq[e * DH + lane];
        #pragma unroll
        for (int r = 0; r < 16; ++r) aq[r] += xb[(r0 + r) * EMB + e] * qw;
      }
      __syncthreads();
      #pragma unroll
      for (int r = 0; r < 16; ++r) Qt[wave*16 + r][lane] = aq[r];
      __syncthreads();
    }
    const int t = tile * 64 + tr;
    float qreg[16];
    {
      const float4* q4 = (const float4*)&Qt[tr][dq * 16];
      #pragma unroll
      for (int i = 0; i < 4; ++i) {
        float4 qv = q4[i];
        qreg[4*i+0] = qv.x; qreg[4*i+1] = qv.y; qreg[4*i+2] = qv.z; qreg[4*i+3] = qv.w;
      }
    }
    float acc[16];
    #pragma unroll
    for (int i = 0; i < 16; ++i) acc[i] = 0.f;
    for (int s2 = 0; s2 <= t; ++s2) {
      const float4* kk4 = (const float4*)&Ks[s2][dq * 16];
      float part = 0.f;
      #pragma unroll
      for (int i = 0; i < 4; ++i) {
        float4 kv = kk4[i];
        part += qreg[4*i+0]*kv.x + qreg[4*i+1]*kv.y + qreg[4*i+2]*kv.z + qreg[4*i+3]*kv.w;
      }
      part += __shfl_xor(part, 1);
      part += __shfl_xor(part, 2);
      const float p = __expf(part * SCALE);
      const float4* vv4 = (const float4*)&Vs[s2][dq * 16];
      #pragma unroll
      for (int i = 0; i < 4; ++i) {
        float4 vv = vv4[i];
        acc[4*i+0] += p * vv.x; acc[4*i+1] += p * vv.y;
        acc[4*i+2] += p * vv.z; acc[4*i+3] += p * vv.w;
      }
    }
    __syncthreads();
    #pragma unroll
    for (int i = 0; i < 16; ++i) Qt[tr][dq*16 + i] = acc[i];
    __syncthreads();
    const int c1 = tid;
    const int c2 = 256 + tid;
    for (int rg = 0; rg < 4; ++rg) {
      float a1[16], a2[16];
      #pragma unroll
      for (int r = 0; r < 16; ++r) { a1[r] = 0.f; a2[r] = 0.f; }
      for (int d = 0; d < 64; ++d) {
        const float wp1 = Wp[(size_t)(h*64 + d) * EMB + c1];
        const float wp2 = (tid < 128) ? Wp[(size_t)(h*64 + d) * EMB + c2] : 0.f;
        #pragma unroll
        for (int r = 0; r < 16; ++r) {
          const float a = Qt[rg*16 + r][d];
          a1[r] += a * wp1; a2[r] += a * wp2;
        }
      }
      if (h == 0) {
        #pragma unroll
        for (int r = 0; r < 16; ++r) { a1[r] += bias1; a2[r] += bias2; }
      }
      const int trow0 = tile*64 + rg*16;
      #pragma unroll
      for (int r = 0; r < 16; ++r)
        atomicAdd(&ob[(size_t)(trow0 + r) * EMB + c1], a1[r]);
      if (tid < 128) {
        #pragma unroll
        for (int r = 0; r < 16; ++r)
          atomicAdd(&ob[(size_t)(trow0 + r) * EMB + c2], a2[r]);
      }
    }
    __syncthreads();
  }
}

extern "C" void kernel_launch(void* const* d_in, const int* in_sizes, int n_in,
                              void* d_out, int out_size, void* d_ws, size_t ws_size,
                              hipStream_t stream) {
  const float* x  = (const float*)d_in[0];
  const float* Wq = (const float*)d_in[1];
  const float* Wk = (const float*)d_in[2];
  const float* Wv = (const float*)d_in[3];
  const float* Wp = (const float*)d_in[4];
  const float* bp = (const float*)d_in[5];

  const int nb = in_sizes[0] / (TT * EMB);       // batch (128)
  const size_t M = (size_t)nb * TT;              // 32768 rows
  const size_t XB = M * EMB * 2;                 // bf16 activation bytes (25 MB)
  const size_t WT = (size_t)1536 * 384 * 2;

  const size_t off_wt = 0;
  const size_t off_o  = off_wt + WT;
  const size_t need   = off_o + XB;

  if (ws_size < need || nb * HEADS != 768) {
    hipMemsetAsync(d_out, 0, (size_t)out_size * sizeof(float), stream);
    mha_fused<<<nb * HEADS, 256, 0, stream>>>(x, Wq, Wk, Wv, Wp, bp, (float*)d_out);
    return;
  }

  char* ws = (char*)d_ws;
  unsigned short* Wt = (unsigned short*)(ws + off_wt);
  unsigned short* Ow = (unsigned short*)(ws + off_o);

  build_wt<<<288, 256, 0, stream>>>(Wq, Wk, Wv, Wp, Wt);

  qkv_attn<<<nb * HEADS, 1024, 0, stream>>>(x, Wt, Ow);

  proj_gemm<<<(unsigned)(M / 128), 512, 0, stream>>>(
      Ow, Wt + (size_t)1152 * 384, (float*)d_out, bp);
}

// Round 18
// 99.272 us; speedup vs baseline: 2.9672x; 1.0158x over previous
//
#include <hip/hip_runtime.h>

#define EMB 384
#define HEADS 6
#define DH 64
#define TT 256

constexpr float SCALE = 0.05103103630798288f;  // 384^-0.5

typedef __attribute__((ext_vector_type(8))) short short8;
typedef __attribute__((ext_vector_type(4))) float f32x4;
typedef __attribute__((ext_vector_type(4))) unsigned short u16x4;

__device__ __forceinline__ unsigned short f2bf(float f) {
  unsigned int u = __builtin_bit_cast(unsigned int, f);
  u += 0x7FFFu + ((u >> 16) & 1u);   // RNE
  return (unsigned short)(u >> 16);
}
__device__ __forceinline__ float bf2f(unsigned short u) {
  unsigned int v = ((unsigned int)u) << 16;
  return __builtin_bit_cast(float, v);
}
__device__ __forceinline__ void gll16(const void* g, void* l) {
  __builtin_amdgcn_global_load_lds(
      (const __attribute__((address_space(1))) unsigned int*)g,
      (__attribute__((address_space(3))) unsigned int*)l, 16, 0, 0);
}

// ---- K0: build Wt[1536][384] bf16. Rows 0..1151: per-HEAD blocks of 192
// (q d0-63 | k d0-63 | v d0-63); rows 1152..1535: proj^T. ----
__global__ __launch_bounds__(256)
void build_wt(const float* __restrict__ Wq, const float* __restrict__ Wk,
              const float* __restrict__ Wv, const float* __restrict__ Wp,
              unsigned short* __restrict__ Wt) {
  int idx = blockIdx.x * 256 + threadIdx.x;  // 1536*48 = 73728
  int n = idx / 48, e0 = (idx % 48) * 8;
  const float* src; int stride;
  if (n < 1152) {
    int h = n / 192, rem = n % 192, qkv = rem >> 6, d = rem & 63;
    const float* W = (qkv == 0) ? Wq : (qkv == 1) ? Wk : Wv;
    src = W + ((size_t)h * EMB + e0) * DH + d; stride = DH;
  } else {
    int c = n - 1152;
    src = Wp + (size_t)e0 * EMB + c; stride = EMB;
  }
  short8 o;
  #pragma unroll
  for (int j = 0; j < 8; ++j) o[j] = (short)f2bf(src[j * stride]);
  ((short8*)Wt)[idx] = o;
}

// ================= fused QKV-GEMM + attention, one block per (b,h) =================
// 1024 thr / 16 waves. A = x fp32 converted in-stage with TWO reg sets:
// step k issues loadA(k+2), writes the set loaded at k-1 (landed -> no wait),
// then computes. writeA chunk map {2q,2q+1}: pos%8 spans 0..7 per 16-lane phase
// group -> 2-way (free) instead of 4-way. XCD swizzle for x L2/L3 locality.
__global__ __launch_bounds__(1024, 1)
void qkv_attn(const float* __restrict__ x, const unsigned short* __restrict__ Wt,
              unsigned short* __restrict__ O)
{
  __shared__ __align__(16) char EL[73728];   // GEMM buf0: A0(32K)+B0(24K); then Qtmp; then E
  __shared__ __align__(16) char KL[32768];   // GEMM buf1 A1; then K [256][64] swizzled
  __shared__ __align__(16) char VL[32768];   // GEMM buf1 B1 (24K); then V^T [64][256] swizzled
  __shared__ float Lpart[16][256];
  __shared__ float invL[256];

  const int bhRaw = blockIdx.x, tid = (int)threadIdx.x;
  const int bh = (bhRaw & 7) * 96 + (bhRaw >> 3);   // 768 = 8*96: bijective XCD swizzle
  const int w = tid >> 6, lane = tid & 63;
  const int la = lane & 15, kh = lane >> 4;
  const int b = bh / 6, h = bh - b * 6;
  const float* xf = x + (size_t)b * 256 * 384;
  const unsigned short* Wb = Wt + (size_t)h * 192 * 384;
  char* A0 = EL;            // 32 KB
  char* B0 = EL + 32768;    // 24 KB
  char* A1 = KL;            // 32 KB (scratch during GEMM)
  char* B1 = VL;            // 24 KB of 32 KB (scratch during GEMM)

  // ---------------- QKV GEMM: wave tile 64 x 48, double-buffered ----------------
  const int wr = (w >> 2) * 64, wc = (w & 3) * 48;
  f32x4 acc[4][3];
  #pragma unroll
  for (int i = 0; i < 4; ++i)
    #pragma unroll
    for (int j = 0; j < 3; ++j) acc[i][j] = f32x4{0.f, 0.f, 0.f, 0.f};

  // A reg-staging: 4 threads/row, thread covers chunks {2q, 2q+1} (8 fp32 each,
  // 32B contiguous global reads; LDS writes conflict-free: pos%8 full coverage)
  const int arow = tid >> 2, aqq = tid & 3;
  const float4* xfr = (const float4*)(xf + (size_t)arow * 384);

  float4 raA[4], raB[4];
  auto loadA = [&](float4 (&ra)[4], int kt) {
    const int base = kt * 16;              // float4 units (64 floats / step)
    #pragma unroll
    for (int i = 0; i < 2; ++i) {
      const int ch = aqq * 2 + i;
      ra[2*i]   = xfr[base + ch * 2];
      ra[2*i+1] = xfr[base + ch * 2 + 1];
    }
  };
  auto writeA = [&](char* A, const float4 (&ra)[4]) {
    #pragma unroll
    for (int i = 0; i < 2; ++i) {
      const int ch = aqq * 2 + i;
      float4 va = ra[2*i], vb = ra[2*i+1];
      short8 o;
      o[0] = (short)f2bf(va.x); o[1] = (short)f2bf(va.y);
      o[2] = (short)f2bf(va.z); o[3] = (short)f2bf(va.w);
      o[4] = (short)f2bf(vb.x); o[5] = (short)f2bf(vb.y);
      o[6] = (short)f2bf(vb.z); o[7] = (short)f2bf(vb.w);
      *(short8*)(A + arow * 128 + ((ch ^ (arow & 7)) << 4)) = o;
    }
  };
  auto stageB = [&](char* B, int kt) {     // gll16, [192][64] bf16, 24KB
    const int Lb0 = tid * 16;
    const int row0 = Lb0 >> 7;
    const int kcs0 = ((Lb0 >> 4) & 7) ^ (row0 & 7);
    gll16(Wb + (size_t)row0 * 384 + kt * 64 + kcs0 * 8, B + Lb0);
    if (tid < 512) {
      const int Lb = 16384 + tid * 16;
      const int row = Lb >> 7;
      const int kcs = ((Lb >> 4) & 7) ^ (row & 7);
      gll16(Wb + (size_t)row * 384 + kt * 64 + kcs * 8, B + Lb);
    }
  };

  auto compute = [&](const char* A, const char* B) {
    #pragma unroll
    for (int kk = 0; kk < 2; ++kk) {
      const int ch = kk * 4 + kh;
      short8 a[4], bfr[3];
      #pragma unroll
      for (int mi = 0; mi < 4; ++mi) {
        const int r = wr + mi * 16 + la;
        a[mi] = *(const short8*)(A + r * 128 + ((ch ^ (r & 7)) << 4));
      }
      #pragma unroll
      for (int ni = 0; ni < 3; ++ni) {
        const int rB = wc + ni * 16 + la;
        bfr[ni] = *(const short8*)(B + rB * 128 + ((ch ^ (rB & 7)) << 4));
      }
      __builtin_amdgcn_s_setprio(1);
      #pragma unroll
      for (int mi = 0; mi < 4; ++mi)
        #pragma unroll
        for (int ni = 0; ni < 3; ++ni)
          acc[mi][ni] = __builtin_amdgcn_mfma_f32_16x16x32_bf16(a[mi], bfr[ni], acc[mi][ni], 0, 0, 0);
      __builtin_amdgcn_s_setprio(0);
    }
  };

  // prologue: raA=x(0) (cold wait in writeA), raB=x(1) in flight
  loadA(raA, 0);
  loadA(raB, 1);
  stageB(B0, 0);
  writeA(A0, raA);
  __syncthreads();                       // A0+B0 ready

  loadA(raA, 2); stageB(B1, 1); writeA(A1, raB); compute(A0, B0);
  __syncthreads();
  loadA(raB, 3); stageB(B0, 2); writeA(A0, raA); compute(A1, B1);
  __syncthreads();
  loadA(raA, 4); stageB(B1, 3); writeA(A1, raB); compute(A0, B0);
  __syncthreads();
  loadA(raB, 5); stageB(B0, 4); writeA(A0, raA); compute(A1, B1);
  __syncthreads();
  stageB(B1, 5); writeA(A1, raB); compute(A0, B0);
  __syncthreads();
  compute(A1, B1);
  __syncthreads();   // all reads of A1/B1 done before epilogue overwrites KL/VL

  // ---- epilogue: Q -> Qtmp (EL, [256][64] swizzled), K -> KL, V^T -> VL ----
  #pragma unroll
  for (int mi = 0; mi < 4; ++mi) {
    #pragma unroll
    for (int ni = 0; ni < 3; ++ni) {
      const int col = wc + ni * 16 + la;
      const int tb = wr + mi * 16 + kh * 4;
      if (col < 64) {
        const int d = col;
        #pragma unroll
        for (int j = 0; j < 4; ++j) {
          const int t = tb + j;
          *(unsigned short*)(EL + t * 128 + (((d >> 3) ^ (t & 7)) << 4) + (d & 7) * 2)
              = f2bf(acc[mi][ni][j]);
        }
      } else if (col < 128) {
        const int d = col - 64;
        #pragma unroll
        for (int j = 0; j < 4; ++j) {
          const int t = tb + j;
          *(unsigned short*)(KL + t * 128 + (((d >> 3) ^ (t & 7)) << 4) + (d & 7) * 2)
              = f2bf(acc[mi][ni][j]);
        }
      } else {
        const int d = col - 128;
        u16x4 pk;
        #pragma unroll
        for (int j = 0; j < 4; ++j) pk[j] = f2bf(acc[mi][ni][j]);
        *(u16x4*)(VL + d * 512 + (((tb >> 3) ^ (d & 7)) << 4) + (tb & 7) * 2) = pk;
      }
    }
  }
  __syncthreads();

  // ---- hoist Q fragments for this wave's PAIR {p, 15-p}, p = w>>1 ----
  const int p = w >> 1;
  const int rts[2] = { p, 15 - p };
  short8 qa[2][2];
  #pragma unroll
  for (int ti = 0; ti < 2; ++ti)
    #pragma unroll
    for (int kk = 0; kk < 2; ++kk) {
      const int r = rts[ti] * 16 + la;
      const int ch = kk * 4 + kh;
      qa[ti][kk] = *(const short8*)(EL + r * 128 + ((ch ^ (r & 7)) << 4));
    }
  __syncthreads();   // EL now free for E strips

  int wps[2], eoffs[2];
  #pragma unroll
  for (int ti = 0; ti < 2; ++ti) {
    const int rt = rts[ti];
    wps[ti] = 32 * ((rt + 2) >> 1);
    const int S = (rt & 1) ? ((rt + 1) * (rt + 1) / 4) : (rt * (rt + 2) / 4);
    eoffs[ti] = 1024 * S;
  }

  // ---- zero own Lpart row (wave-local) ----
  #pragma unroll
  for (int i = 0; i < 4; ++i) Lpart[w][i * 64 + lane] = 0.f;

  // ---- QK^T + masked exp -> E strips; ns-parity split across the pair's waves ----
  #pragma unroll
  for (int ti = 0; ti < 2; ++ti) {
    const int rt = rts[ti], wp = wps[ti], stride = wp * 2;
    char* Ebase = EL + eoffs[ti];
    const int nns = wp >> 4;
    for (int ns = (w & 1); ns < nns; ns += 2) {
      f32x4 s4 = f32x4{0.f, 0.f, 0.f, 0.f};
      #pragma unroll
      for (int kk = 0; kk < 2; ++kk) {
        const int rB = ns * 16 + la, kc = kk * 4 + kh;
        short8 bf = *(const short8*)(KL + rB * 128 + ((kc ^ (rB & 7)) << 4));
        s4 = __builtin_amdgcn_mfma_f32_16x16x32_bf16(qa[ti][kk], bf, s4, 0, 0, 0);
      }
      const int c = ns * 16 + la, cc = c >> 3, co = (c & 7) * 2;
      float ps = 0.f;
      #pragma unroll
      for (int j = 0; j < 4; ++j) {
        const int r = kh * 4 + j;
        const int t = rt * 16 + r;
        const float e = (t >= c) ? __expf(s4[j] * SCALE) : 0.f;
        ps += e;
        *(unsigned short*)(Ebase + r * stride + ((cc ^ (r & 3)) << 4) + co) = f2bf(e);
      }
      ps += __shfl_xor(ps, 16);
      ps += __shfl_xor(ps, 32);        // 16-row tile-column sum in all kh lanes
      if (kh == 0) Lpart[w][c] += ps;  // wave-local row: no race
    }
  }
  __syncthreads();

  if (tid < 256) {
    float Ls = 0.f;
    #pragma unroll
    for (int ww = 0; ww < 16; ++ww) Ls += Lpart[ww][tid];
    invL[tid] = 1.f / Ls;
  }
  __syncthreads();

  // ---- fold 1/L_s into V (1024 threads: 2 chunks each) ----
  {
    const int d = tid >> 4, qq = tid & 15;
    #pragma unroll
    for (int i = 0; i < 2; ++i) {
      const int kcp = qq * 2 + i;
      char* pch = VL + d * 512 + kcp * 16;
      short8 v = *(short8*)pch;
      const int sb = (kcp ^ (d & 7)) * 8;
      short8 o;
      #pragma unroll
      for (int e = 0; e < 8; ++e)
        o[e] = (short)f2bf(bf2f((unsigned short)v[e]) * invL[sb + e]);
      *(short8*)pch = o;
    }
  }
  __syncthreads();

  // ---- O = E * V': big tile to wave bigw = 2p + ((p>>1)&1) (SIMD-balanced) ----
  unsigned short* Og = O + (size_t)b * 256 * 384 + h * 64;
  {
    const int bigw = 2 * p + ((p >> 1) & 1);
    const int ti = (w == bigw) ? 1 : 0;
    const int rt = rts[ti], wp = wps[ti], stride = wp * 2;
    const char* Ebase = EL + eoffs[ti];
    f32x4 oacc[4];
    #pragma unroll
    for (int nd = 0; nd < 4; ++nd) oacc[nd] = f32x4{0.f, 0.f, 0.f, 0.f};
    const int nks = wp >> 5;
    for (int ks = 0; ks < nks; ++ks) {
      const int cc = ks * 4 + kh;
      short8 ea = *(const short8*)(Ebase + la * stride + ((cc ^ (la & 3)) << 4));
      __builtin_amdgcn_s_setprio(1);
      #pragma unroll
      for (int nd = 0; nd < 4; ++nd) {
        const int d = nd * 16 + la;
        short8 vb = *(const short8*)(VL + d * 512 + ((cc ^ (d & 7)) << 4));
        oacc[nd] = __builtin_amdgcn_mfma_f32_16x16x32_bf16(ea, vb, oacc[nd], 0, 0, 0);
      }
      __builtin_amdgcn_s_setprio(0);
    }
    #pragma unroll
    for (int nd = 0; nd < 4; ++nd) {
      const int d = nd * 16 + la;
      #pragma unroll
      for (int j = 0; j < 4; ++j) {
        const int t = rt * 16 + kh * 4 + j;
        Og[(size_t)t * 384 + d] = f2bf(oacc[nd][j]);
      }
    }
  }
}

// ---------------- proj GEMM: out = O * proj + bias (XCD-swizzled) ----------------
// 1024 thr / 16 waves (4/SIMD): wave grid 4x4 on the 128x128 tile, acc[2][2].
__global__ __launch_bounds__(1024, 1)
void proj_gemm(const unsigned short* __restrict__ A, const unsigned short* __restrict__ Bt,
               float* __restrict__ Co, const float* __restrict__ bias)
{
  __shared__ __align__(16) unsigned short AL[128 * 384];    // 96 KB
  __shared__ __align__(16) unsigned short BL[2][128 * 64];  // 2 x 16 KB
  const int tid = (int)threadIdx.x, w = tid >> 6, lane = tid & 63;
  const int la = lane & 15, kh = lane >> 4;
  // 256 = 8*32 bijective swizzle: same-XCD as the qkv blocks that wrote these rows
  const int mt = ((int)blockIdx.x & 7) * 32 + ((int)blockIdx.x >> 3);
  const int m0 = mt * 128;

  {
    const int row = tid >> 3, qq = tid & 7;     // 8 threads/row, 6 chunks each
    const short8* O8 = (const short8*)(A + (size_t)(m0 + row) * 384);
    #pragma unroll
    for (int i = 0; i < 6; ++i) {
      const int ch = qq + 8 * i;
      *(short8*)((char*)AL + row * 768 + ((ch ^ (row & 7)) << 4)) = O8[ch];
    }
  }

  auto stageB = [&](int buf, int n0, int k0) {
    const int Lb = tid * 16;                    // 1024 x 16B = 16KB
    const int row = Lb >> 7;
    const int kcs = ((Lb >> 4) & 7) ^ (row & 7);
    gll16(Bt + (size_t)(n0 + row) * 384 + k0 + kcs * 8, (char*)BL[buf] + Lb);
  };

  stageB(0, 0, 0);
  __syncthreads();

  const int wr = (w >> 2) * 32, wc = (w & 3) * 32;
  int buf = 0;
  for (int nt = 0; nt < 3; ++nt) {
    f32x4 acc[2][2];
    #pragma unroll
    for (int i = 0; i < 2; ++i) { acc[i][0] = f32x4{0.f,0.f,0.f,0.f}; acc[i][1] = f32x4{0.f,0.f,0.f,0.f}; }

    for (int kt = 0; kt < 6; ++kt) {
      if (kt < 5)          stageB(buf ^ 1, nt * 128, (kt + 1) * 64);
      else if (nt + 1 < 3) stageB(buf ^ 1, (nt + 1) * 128, 0);
      #pragma unroll
      for (int kk = 0; kk < 2; ++kk) {
        short8 a[2], bb[2];
        const int chA = kt * 8 + kk * 4 + kh;
        #pragma unroll
        for (int mi = 0; mi < 2; ++mi) {
          const int r = wr + mi * 16 + la;
          a[mi] = *(const short8*)((const char*)AL + r * 768 + ((chA ^ (r & 7)) << 4));
        }
        const int chB = kk * 4 + kh;
        #pragma unroll
        for (int ni = 0; ni < 2; ++ni) {
          const int rB = wc + ni * 16 + la;
          bb[ni] = *(const short8*)((const char*)BL[buf] + rB * 128 + ((chB ^ (rB & 7)) << 4));
        }
        __builtin_amdgcn_s_setprio(1);
        #pragma unroll
        for (int mi = 0; mi < 2; ++mi)
          #pragma unroll
          for (int ni = 0; ni < 2; ++ni)
            acc[mi][ni] = __builtin_amdgcn_mfma_f32_16x16x32_bf16(a[mi], bb[ni], acc[mi][ni], 0, 0, 0);
        __builtin_amdgcn_s_setprio(0);
      }
      __syncthreads();
      buf ^= 1;
    }

    #pragma unroll
    for (int mi = 0; mi < 2; ++mi) {
      const int mbase = m0 + wr + mi * 16 + kh * 4;
      #pragma unroll
      for (int ni = 0; ni < 2; ++ni) {
        const int nl = nt * 128 + wc + ni * 16 + la;
        const float bn = bias[nl];
        #pragma unroll
        for (int j = 0; j < 4; ++j)
          Co[(size_t)(mbase + j) * 384 + nl] = acc[mi][ni][j] + bn;
      }
    }
  }
}

// ================= fallback (fp32) for small ws =================
__global__ __launch_bounds__(256, 1)
void mha_fused(const float* __restrict__ x, const float* __restrict__ Wq,
               const float* __restrict__ Wk, const float* __restrict__ Wv,
               const float* __restrict__ Wp, const float* __restrict__ bp,
               float* __restrict__ out)
{
  const int bh = blockIdx.x;
  const int b = bh / HEADS, h = bh % HEADS;
  const int tid = (int)threadIdx.x;
  const int wave = tid >> 6, lane = tid & 63;
  const float* xb = x + (size_t)b * TT * EMB;
  const float* wq = Wq + (size_t)h * EMB * DH;
  const float* wk = Wk + (size_t)h * EMB * DH;
  const float* wv = Wv + (size_t)h * EMB * DH;
  __shared__ float Ks[TT][68];
  __shared__ float Vs[TT][64];
  __shared__ float Qt[64][68];
  for (int c = 0; c < 4; ++c) {
    const int s0 = wave * 64 + c * 16;
    float ak[16], av[16];
    #pragma unroll
    for (int r = 0; r < 16; ++r) { ak[r] = 0.f; av[r] = 0.f; }
    for (int e = 0; e < EMB; ++e) {
      const float kk = wk[e * DH + lane];
      const float vv = wv[e * DH + lane];
      #pragma unroll
      for (int r = 0; r < 16; ++r) {
        const float xv = xb[(s0 + r) * EMB + e];
        ak[r] += xv * kk; av[r] += xv * vv;
      }
    }
    #pragma unroll
    for (int r = 0; r < 16; ++r) { Ks[s0 + r][lane] = ak[r]; Vs[s0 + r][lane] = av[r]; }
  }
  __syncthreads();
  const int s = tid;
  float kreg[64];
  {
    const float4* k4 = (const float4*)&Ks[s][0];
    #pragma unroll
    for (int i = 0; i < 16; ++i) {
      float4 kv = k4[i];
      kreg[4*i+0] = kv.x; kreg[4*i+1] = kv.y; kreg[4*i+2] = kv.z; kreg[4*i+3] = kv.w;
    }
  }
  float Lsum = 0.f;
  for (int tile = 0; tile < 4; ++tile) {
    {
      const int r0 = tile * 64 + wave * 16;
      float aq[16];
      #pragma unroll
      for (int r = 0; r < 16; ++r) aq[r] = 0.f;
      for (int e = 0; e < EMB; ++e) {
        const float qw = wq[e * DH + lane];
        #pragma unroll
        for (int r = 0; r < 16; ++r) aq[r] += xb[(r0 + r) * EMB + e] * qw;
      }
      __syncthreads();
      #pragma unroll
      for (int r = 0; r < 16; ++r) Qt[wave*16 + r][lane] = aq[r];
      __syncthreads();
    }
    const int tbase = tile * 64;
    if (tbase + 63 >= s) {
      for (int tr = 0; tr < 64; ++tr) {
        const int t = tbase + tr;
        if (t < s) continue;
        float w = 0.f;
        const float4* q4 = (const float4*)&Qt[tr][0];
        #pragma unroll
        for (int i = 0; i < 16; ++i) {
          float4 qv = q4[i];
          w += qv.x*kreg[4*i+0] + qv.y*kreg[4*i+1] + qv.z*kreg[4*i+2] + qv.w*kreg[4*i+3];
        }
        Lsum += __expf(w * SCALE);
      }
    }
  }
  __syncthreads();
  {
    const float invL = 1.0f / Lsum;
    float4* v4 = (float4*)&Vs[s][0];
    #pragma unroll
    for (int i = 0; i < 16; ++i) {
      float4 vv = v4[i];
      vv.x *= invL; vv.y *= invL; vv.z *= invL; vv.w *= invL;
      v4[i] = vv;
    }
  }
  __syncthreads();
  const float bias1 = bp[tid];
  const float bias2 = (tid < 128) ? bp[256 + tid] : 0.f;
  const int tr = tid >> 2, dq = tid & 3;
  float* ob = out + (size_t)b * TT * EMB;
  for (int tile = 0; tile < 4; ++tile) {
    {
      const int r0 = tile * 64 + wave * 16;
      float aq[16];
      #pragma unroll
      for (int r = 0; r < 16; ++r) aq[r] = 0.f;
      for (int e = 0; e < EMB; ++e) {
        const float qw = wq[e * DH + lane];
        #pragma unroll
        for (int r = 0; r < 16; ++r) aq[r] += xb[(r0 + r) * EMB + e] * qw;
      }
      __syncthreads();
      #pragma unroll
      for (int r = 0; r < 16; ++r) Qt[wave*16 + r][lane] = aq[r];
      __syncthreads();
    }
    const int t = tile * 64 + tr;
    float qreg[16];
    {
      const float4* q4 = (const float4*)&Qt[tr][dq * 16];
      #pragma unroll
      for (int i = 0; i < 4; ++i) {
        float4 qv = q4[i];
        qreg[4*i+0] = qv.x; qreg[4*i+1] = qv.y; qreg[4*i+2] = qv.z; qreg[4*i+3] = qv.w;
      }
    }
    float acc[16];
    #pragma unroll
    for (int i = 0; i < 16; ++i) acc[i] = 0.f;
    for (int s2 = 0; s2 <= t; ++s2) {
      const float4* kk4 = (const float4*)&Ks[s2][dq * 16];
      float part = 0.f;
      #pragma unroll
      for (int i = 0; i < 4; ++i) {
        float4 kv = kk4[i];
        part += qreg[4*i+0]*kv.x + qreg[4*i+1]*kv.y + qreg[4*i+2]*kv.z + qreg[4*i+3]*kv.w;
      }
      part += __shfl_xor(part, 1);
      part += __shfl_xor(part, 2);
      const float p = __expf(part * SCALE);
      const float4* vv4 = (const float4*)&Vs[s2][dq * 16];
      #pragma unroll
      for (int i = 0; i < 4; ++i) {
        float4 vv = vv4[i];
        acc[4*i+0] += p * vv.x; acc[4*i+1] += p * vv.y;
        acc[4*i+2] += p * vv.z; acc[4*i+3] += p * vv.w;
      }
    }
    __syncthreads();
    #pragma unroll
    for (int i = 0; i < 16; ++i) Qt[tr][dq*16 + i] = acc[i];
    __syncthreads();
    const int c1 = tid;
    const int c2 = 256 + tid;
    for (int rg = 0; rg < 4; ++rg) {
      float a1[16], a2[16];
      #pragma unroll
      for (int r = 0; r < 16; ++r) { a1[r] = 0.f; a2[r] = 0.f; }
      for (int d = 0; d < 64; ++d) {
        const float wp1 = Wp[(size_t)(h*64 + d) * EMB + c1];
        const float wp2 = (tid < 128) ? Wp[(size_t)(h*64 + d) * EMB + c2] : 0.f;
        #pragma unroll
        for (int r = 0; r < 16; ++r) {
          const float a = Qt[rg*16 + r][d];
          a1[r] += a * wp1; a2[r] += a * wp2;
        }
      }
      if (h == 0) {
        #pragma unroll
        for (int r = 0; r < 16; ++r) { a1[r] += bias1; a2[r] += bias2; }
      }
      const int trow0 = tile*64 + rg*16;
      #pragma unroll
      for (int r = 0; r < 16; ++r)
        atomicAdd(&ob[(size_t)(trow0 + r) * EMB + c1], a1[r]);
      if (tid < 128) {
        #pragma unroll
        for (int r = 0; r < 16; ++r)
          atomicAdd(&ob[(size_t)(trow0 + r) * EMB + c2], a2[r]);
      }
    }
    __syncthreads();
  }
}

extern "C" void kernel_launch(void* const* d_in, const int* in_sizes, int n_in,
                              void* d_out, int out_size, void* d_ws, size_t ws_size,
                              hipStream_t stream) {
  const float* x  = (const float*)d_in[0];
  const float* Wq = (const float*)d_in[1];
  const float* Wk = (const float*)d_in[2];
  const float* Wv = (const float*)d_in[3];
  const float* Wp = (const float*)d_in[4];
  const float* bp = (const float*)d_in[5];

  const int nb = in_sizes[0] / (TT * EMB);       // batch (128)
  const size_t M = (size_t)nb * TT;              // 32768 rows
  const size_t XB = M * EMB * 2;                 // bf16 activation bytes (25 MB)
  const size_t WT = (size_t)1536 * 384 * 2;

  const size_t off_wt = 0;
  const size_t off_o  = off_wt + WT;
  const size_t need   = off_o + XB;

  if (ws_size < need || nb * HEADS != 768) {
    hipMemsetAsync(d_out, 0, (size_t)out_size * sizeof(float), stream);
    mha_fused<<<nb * HEADS, 256, 0, stream>>>(x, Wq, Wk, Wv, Wp, bp, (float*)d_out);
    return;
  }

  char* ws = (char*)d_ws;
  unsigned short* Wt = (unsigned short*)(ws + off_wt);
  unsigned short* Ow = (unsigned short*)(ws + off_o);

  build_wt<<<288, 256, 0, stream>>>(Wq, Wk, Wv, Wp, Wt);

  qkv_attn<<<nb * HEADS, 1024, 0, stream>>>(x, Wt, Ow);

  proj_gemm<<<(unsigned)(M / 128), 1024, 0, stream>>>(
      Ow, Wt + (size_t)1152 * 384, (float*)d_out, bp);
}

// Round 20
// 97.895 us; speedup vs baseline: 3.0089x; 1.0141x over previous
//
#include <hip/hip_runtime.h>
#include <hip/hip_bf16.h>

#define EMB 384
#define HEADS 6
#define DH 64
#define TT 256

constexpr float SCALE = 0.05103103630798288f;  // 384^-0.5

typedef __attribute__((ext_vector_type(8))) short short8;
typedef __attribute__((ext_vector_type(4))) float f32x4;
typedef __attribute__((ext_vector_type(4))) unsigned short u16x4;

__device__ __forceinline__ unsigned short f2bf(float f) {
  __hip_bfloat16 h = __float2bfloat16(f);          // compiler-lowered RNE
  unsigned short u;
  __builtin_memcpy(&u, &h, 2);
  return u;
}
__device__ __forceinline__ unsigned int f2bf2(float lo, float hi) {
  __hip_bfloat162 h = __float22bfloat162_rn(float2{lo, hi});  // v_cvt_pk_bf16_f32
  unsigned int u;
  __builtin_memcpy(&u, &h, 4);
  return u;
}
__device__ __forceinline__ float bf2f(unsigned short u) {
  unsigned int v = ((unsigned int)u) << 16;
  return __builtin_bit_cast(float, v);
}
__device__ __forceinline__ void gll16(const void* g, void* l) {
  __builtin_amdgcn_global_load_lds(
      (const __attribute__((address_space(1))) unsigned int*)g,
      (__attribute__((address_space(3))) unsigned int*)l, 16, 0, 0);
}

// ---- K0: build Wt[1536][384] bf16. Rows 0..1151: per-HEAD blocks of 192
// (q d0-63 | k d0-63 | v d0-63); rows 1152..1535: proj^T. ----
__global__ __launch_bounds__(256)
void build_wt(const float* __restrict__ Wq, const float* __restrict__ Wk,
              const float* __restrict__ Wv, const float* __restrict__ Wp,
              unsigned short* __restrict__ Wt) {
  int idx = blockIdx.x * 256 + threadIdx.x;  // 1536*48 = 73728
  int n = idx / 48, e0 = (idx % 48) * 8;
  const float* src; int stride;
  if (n < 1152) {
    int h = n / 192, rem = n % 192, qkv = rem >> 6, d = rem & 63;
    const float* W = (qkv == 0) ? Wq : (qkv == 1) ? Wk : Wv;
    src = W + ((size_t)h * EMB + e0) * DH + d; stride = DH;
  } else {
    int c = n - 1152;
    src = Wp + (size_t)e0 * EMB + c; stride = EMB;
  }
  short8 o;
  #pragma unroll
  for (int j = 0; j < 8; ++j) o[j] = (short)f2bf(src[j * stride]);
  ((short8*)Wt)[idx] = o;
}

// ================= fused QKV-GEMM + attention, one block per (b,h) =================
// 1024 thr / 16 waves. A = x fp32 converted in-stage (cvt_pk pairs) with TWO reg
// sets: step k issues loadA(k+2), writes set loaded at k-1 (landed -> no wait),
// then computes. XCD swizzle for x L2/L3 locality.
__global__ __launch_bounds__(1024, 1)
void qkv_attn(const float* __restrict__ x, const unsigned short* __restrict__ Wt,
              unsigned short* __restrict__ O)
{
  __shared__ __align__(16) char EL[73728];   // GEMM buf0: A0(32K)+B0(24K); then Qtmp; then E
  __shared__ __align__(16) char KL[32768];   // GEMM buf1 A1; then K [256][64] swizzled
  __shared__ __align__(16) char VL[32768];   // GEMM buf1 B1 (24K); then V^T [64][256] swizzled
  __shared__ float Lpart[16][256];
  __shared__ float invL[256];

  const int bhRaw = blockIdx.x, tid = (int)threadIdx.x;
  const int bh = (bhRaw & 7) * 96 + (bhRaw >> 3);   // 768 = 8*96: bijective XCD swizzle
  const int w = tid >> 6, lane = tid & 63;
  const int la = lane & 15, kh = lane >> 4;
  const int b = bh / 6, h = bh - b * 6;
  const float* xf = x + (size_t)b * 256 * 384;
  const unsigned short* Wb = Wt + (size_t)h * 192 * 384;
  char* A0 = EL;            // 32 KB
  char* B0 = EL + 32768;    // 24 KB
  char* A1 = KL;            // 32 KB (scratch during GEMM)
  char* B1 = VL;            // 24 KB of 32 KB (scratch during GEMM)

  // ---------------- QKV GEMM: wave tile 64 x 48, double-buffered ----------------
  const int wr = (w >> 2) * 64, wc = (w & 3) * 48;
  f32x4 acc[4][3];
  #pragma unroll
  for (int i = 0; i < 4; ++i)
    #pragma unroll
    for (int j = 0; j < 3; ++j) acc[i][j] = f32x4{0.f, 0.f, 0.f, 0.f};

  // A reg-staging: 4 threads/row, thread covers chunks {2q, 2q+1}
  const int arow = tid >> 2, aqq = tid & 3;
  const float4* xfr = (const float4*)(xf + (size_t)arow * 384);

  float4 raA[4], raB[4];
  auto loadA = [&](float4 (&ra)[4], int kt) {
    const int base = kt * 16;              // float4 units (64 floats / step)
    #pragma unroll
    for (int i = 0; i < 2; ++i) {
      const int ch = aqq * 2 + i;
      ra[2*i]   = xfr[base + ch * 2];
      ra[2*i+1] = xfr[base + ch * 2 + 1];
    }
  };
  auto writeA = [&](char* A, const float4 (&ra)[4]) {
    #pragma unroll
    for (int i = 0; i < 2; ++i) {
      const int ch = aqq * 2 + i;
      float4 va = ra[2*i], vb = ra[2*i+1];
      union { short8 s; unsigned int u[4]; } cv;
      cv.u[0] = f2bf2(va.x, va.y);
      cv.u[1] = f2bf2(va.z, va.w);
      cv.u[2] = f2bf2(vb.x, vb.y);
      cv.u[3] = f2bf2(vb.z, vb.w);
      *(short8*)(A + arow * 128 + ((ch ^ (arow & 7)) << 4)) = cv.s;
    }
  };
  auto stageB = [&](char* B, int kt) {     // gll16, [192][64] bf16, 24KB
    const int Lb0 = tid * 16;
    const int row0 = Lb0 >> 7;
    const int kcs0 = ((Lb0 >> 4) & 7) ^ (row0 & 7);
    gll16(Wb + (size_t)row0 * 384 + kt * 64 + kcs0 * 8, B + Lb0);
    if (tid < 512) {
      const int Lb = 16384 + tid * 16;
      const int row = Lb >> 7;
      const int kcs = ((Lb >> 4) & 7) ^ (row & 7);
      gll16(Wb + (size_t)row * 384 + kt * 64 + kcs * 8, B + Lb);
    }
  };

  auto compute = [&](const char* A, const char* B) {
    #pragma unroll
    for (int kk = 0; kk < 2; ++kk) {
      const int ch = kk * 4 + kh;
      short8 a[4], bfr[3];
      #pragma unroll
      for (int mi = 0; mi < 4; ++mi) {
        const int r = wr + mi * 16 + la;
        a[mi] = *(const short8*)(A + r * 128 + ((ch ^ (r & 7)) << 4));
      }
      #pragma unroll
      for (int ni = 0; ni < 3; ++ni) {
        const int rB = wc + ni * 16 + la;
        bfr[ni] = *(const short8*)(B + rB * 128 + ((ch ^ (rB & 7)) << 4));
      }
      __builtin_amdgcn_s_setprio(1);
      #pragma unroll
      for (int mi = 0; mi < 4; ++mi)
        #pragma unroll
        for (int ni = 0; ni < 3; ++ni)
          acc[mi][ni] = __builtin_amdgcn_mfma_f32_16x16x32_bf16(a[mi], bfr[ni], acc[mi][ni], 0, 0, 0);
      __builtin_amdgcn_s_setprio(0);
    }
  };

  // prologue: raA=x(0) (cold wait in writeA), raB=x(1) in flight
  loadA(raA, 0);
  loadA(raB, 1);
  stageB(B0, 0);
  writeA(A0, raA);
  __syncthreads();                       // A0+B0 ready

  loadA(raA, 2); stageB(B1, 1); writeA(A1, raB); compute(A0, B0);
  __syncthreads();
  loadA(raB, 3); stageB(B0, 2); writeA(A0, raA); compute(A1, B1);
  __syncthreads();
  loadA(raA, 4); stageB(B1, 3); writeA(A1, raB); compute(A0, B0);
  __syncthreads();
  loadA(raB, 5); stageB(B0, 4); writeA(A0, raA); compute(A1, B1);
  __syncthreads();
  stageB(B1, 5); writeA(A1, raB); compute(A0, B0);
  __syncthreads();
  compute(A1, B1);
  __syncthreads();   // all reads of A1/B1 done before epilogue overwrites KL/VL

  // ---- epilogue: Q -> Qtmp (EL, [256][64] swizzled), K -> KL, V^T -> VL ----
  #pragma unroll
  for (int mi = 0; mi < 4; ++mi) {
    #pragma unroll
    for (int ni = 0; ni < 3; ++ni) {
      const int col = wc + ni * 16 + la;
      const int tb = wr + mi * 16 + kh * 4;
      if (col < 64) {
        const int d = col;
        #pragma unroll
        for (int j = 0; j < 4; ++j) {
          const int t = tb + j;
          *(unsigned short*)(EL + t * 128 + (((d >> 3) ^ (t & 7)) << 4) + (d & 7) * 2)
              = f2bf(acc[mi][ni][j]);
        }
      } else if (col < 128) {
        const int d = col - 64;
        #pragma unroll
        for (int j = 0; j < 4; ++j) {
          const int t = tb + j;
          *(unsigned short*)(KL + t * 128 + (((d >> 3) ^ (t & 7)) << 4) + (d & 7) * 2)
              = f2bf(acc[mi][ni][j]);
        }
      } else {
        const int d = col - 128;
        union { u16x4 p; unsigned int u[2]; } cv;
        cv.u[0] = f2bf2(acc[mi][ni][0], acc[mi][ni][1]);
        cv.u[1] = f2bf2(acc[mi][ni][2], acc[mi][ni][3]);
        *(u16x4*)(VL + d * 512 + (((tb >> 3) ^ (d & 7)) << 4) + (tb & 7) * 2) = cv.p;
      }
    }
  }
  __syncthreads();

  // ---- hoist Q fragments for this wave's PAIR {p, 15-p}, p = w>>1 ----
  const int p = w >> 1;
  const int rts[2] = { p, 15 - p };
  short8 qa[2][2];
  #pragma unroll
  for (int ti = 0; ti < 2; ++ti)
    #pragma unroll
    for (int kk = 0; kk < 2; ++kk) {
      const int r = rts[ti] * 16 + la;
      const int ch = kk * 4 + kh;
      qa[ti][kk] = *(const short8*)(EL + r * 128 + ((ch ^ (r & 7)) << 4));
    }
  __syncthreads();   // EL now free for E strips

  int wps[2], eoffs[2];
  #pragma unroll
  for (int ti = 0; ti < 2; ++ti) {
    const int rt = rts[ti];
    wps[ti] = 32 * ((rt + 2) >> 1);
    const int S = (rt & 1) ? ((rt + 1) * (rt + 1) / 4) : (rt * (rt + 2) / 4);
    eoffs[ti] = 1024 * S;
  }

  // ---- zero own Lpart row (wave-local) ----
  #pragma unroll
  for (int i = 0; i < 4; ++i) Lpart[w][i * 64 + lane] = 0.f;

  // ---- QK^T + masked exp -> E strips; ns-parity split across the pair's waves ----
  #pragma unroll
  for (int ti = 0; ti < 2; ++ti) {
    const int rt = rts[ti], wp = wps[ti], stride = wp * 2;
    char* Ebase = EL + eoffs[ti];
    const int nns = wp >> 4;
    for (int ns = (w & 1); ns < nns; ns += 2) {
      f32x4 s4 = f32x4{0.f, 0.f, 0.f, 0.f};
      #pragma unroll
      for (int kk = 0; kk < 2; ++kk) {
        const int rB = ns * 16 + la, kc = kk * 4 + kh;
        short8 bf = *(const short8*)(KL + rB * 128 + ((kc ^ (rB & 7)) << 4));
        s4 = __builtin_amdgcn_mfma_f32_16x16x32_bf16(qa[ti][kk], bf, s4, 0, 0, 0);
      }
      const int c = ns * 16 + la, cc = c >> 3, co = (c & 7) * 2;
      float ps = 0.f;
      #pragma unroll
      for (int j = 0; j < 4; ++j) {
        const int r = kh * 4 + j;
        const int t = rt * 16 + r;
        const float e = (t >= c) ? __expf(s4[j] * SCALE) : 0.f;
        ps += e;
        *(unsigned short*)(Ebase + r * stride + ((cc ^ (r & 3)) << 4) + co) = f2bf(e);
      }
      ps += __shfl_xor(ps, 16);
      ps += __shfl_xor(ps, 32);        // 16-row tile-column sum in all kh lanes
      if (kh == 0) Lpart[w][c] += ps;  // wave-local row: no race
    }
  }
  __syncthreads();

  if (tid < 256) {
    float Ls = 0.f;
    #pragma unroll
    for (int ww = 0; ww < 16; ++ww) Ls += Lpart[ww][tid];
    invL[tid] = 1.f / Ls;
  }
  __syncthreads();

  // ---- fold 1/L_s into V (1024 threads: 2 chunks each) ----
  {
    const int d = tid >> 4, qq = tid & 15;
    #pragma unroll
    for (int i = 0; i < 2; ++i) {
      const int kcp = qq * 2 + i;
      char* pch = VL + d * 512 + kcp * 16;
      short8 v = *(short8*)pch;
      const int sb = (kcp ^ (d & 7)) * 8;
      union { short8 s; unsigned int u[4]; } cv;
      #pragma unroll
      for (int e = 0; e < 4; ++e)
        cv.u[e] = f2bf2(bf2f((unsigned short)v[2*e])     * invL[sb + 2*e],
                        bf2f((unsigned short)v[2*e + 1]) * invL[sb + 2*e + 1]);
      *(short8*)pch = cv.s;
    }
  }
  __syncthreads();

  // ---- O = E * V': big tile to wave bigw = 2p + ((p>>1)&1) (SIMD-balanced) ----
  unsigned short* Og = O + (size_t)b * 256 * 384 + h * 64;
  {
    const int bigw = 2 * p + ((p >> 1) & 1);
    const int ti = (w == bigw) ? 1 : 0;
    const int rt = rts[ti], wp = wps[ti], stride = wp * 2;
    const char* Ebase = EL + eoffs[ti];
    f32x4 oacc[4];
    #pragma unroll
    for (int nd = 0; nd < 4; ++nd) oacc[nd] = f32x4{0.f, 0.f, 0.f, 0.f};
    const int nks = wp >> 5;
    for (int ks = 0; ks < nks; ++ks) {
      const int cc = ks * 4 + kh;
      short8 ea = *(const short8*)(Ebase + la * stride + ((cc ^ (la & 3)) << 4));
      __builtin_amdgcn_s_setprio(1);
      #pragma unroll
      for (int nd = 0; nd < 4; ++nd) {
        const int d = nd * 16 + la;
        short8 vb = *(const short8*)(VL + d * 512 + ((cc ^ (d & 7)) << 4));
        oacc[nd] = __builtin_amdgcn_mfma_f32_16x16x32_bf16(ea, vb, oacc[nd], 0, 0, 0);
      }
      __builtin_amdgcn_s_setprio(0);
    }
    #pragma unroll
    for (int nd = 0; nd < 4; ++nd) {
      const int d = nd * 16 + la;
      #pragma unroll
      for (int j = 0; j < 4; ++j) {
        const int t = rt * 16 + kh * 4 + j;
        Og[(size_t)t * 384 + d] = f2bf(oacc[nd][j]);
      }
    }
  }
}

// ---------------- proj GEMM: out = O * proj + bias (XCD-swizzled) ----------------
// 1024 thr / 16 waves (4/SIMD): wave grid 4x4 on the 128x128 tile, acc[2][2].
__global__ __launch_bounds__(1024, 1)
void proj_gemm(const unsigned short* __restrict__ A, const unsigned short* __restrict__ Bt,
               float* __restrict__ Co, const float* __restrict__ bias)
{
  __shared__ __align__(16) unsigned short AL[128 * 384];    // 96 KB
  __shared__ __align__(16) unsigned short BL[2][128 * 64];  // 2 x 16 KB
  const int tid = (int)threadIdx.x, w = tid >> 6, lane = tid & 63;
  const int la = lane & 15, kh = lane >> 4;
  // 256 = 8*32 bijective swizzle: same-XCD as the qkv blocks that wrote these rows
  const int mt = ((int)blockIdx.x & 7) * 32 + ((int)blockIdx.x >> 3);
  const int m0 = mt * 128;

  {
    const int row = tid >> 3, qq = tid & 7;     // 8 threads/row, 6 chunks each
    const short8* O8 = (const short8*)(A + (size_t)(m0 + row) * 384);
    #pragma unroll
    for (int i = 0; i < 6; ++i) {
      const int ch = qq + 8 * i;
      *(short8*)((char*)AL + row * 768 + ((ch ^ (row & 7)) << 4)) = O8[ch];
    }
  }

  auto stageB = [&](int buf, int n0, int k0) {
    const int Lb = tid * 16;                    // 1024 x 16B = 16KB
    const int row = Lb >> 7;
    const int kcs = ((Lb >> 4) & 7) ^ (row & 7);
    gll16(Bt + (size_t)(n0 + row) * 384 + k0 + kcs * 8, (char*)BL[buf] + Lb);
  };

  stageB(0, 0, 0);
  __syncthreads();

  const int wr = (w >> 2) * 32, wc = (w & 3) * 32;
  int buf = 0;
  for (int nt = 0; nt < 3; ++nt) {
    f32x4 acc[2][2];
    #pragma unroll
    for (int i = 0; i < 2; ++i) { acc[i][0] = f32x4{0.f,0.f,0.f,0.f}; acc[i][1] = f32x4{0.f,0.f,0.f,0.f}; }

    for (int kt = 0; kt < 6; ++kt) {
      if (kt < 5)          stageB(buf ^ 1, nt * 128, (kt + 1) * 64);
      else if (nt + 1 < 3) stageB(buf ^ 1, (nt + 1) * 128, 0);
      #pragma unroll
      for (int kk = 0; kk < 2; ++kk) {
        short8 a[2], bb[2];
        const int chA = kt * 8 + kk * 4 + kh;
        #pragma unroll
        for (int mi = 0; mi < 2; ++mi) {
          const int r = wr + mi * 16 + la;
          a[mi] = *(const short8*)((const char*)AL + r * 768 + ((chA ^ (r & 7)) << 4));
        }
        const int chB = kk * 4 + kh;
        #pragma unroll
        for (int ni = 0; ni < 2; ++ni) {
          const int rB = wc + ni * 16 + la;
          bb[ni] = *(const short8*)((const char*)BL[buf] + rB * 128 + ((chB ^ (rB & 7)) << 4));
        }
        __builtin_amdgcn_s_setprio(1);
        #pragma unroll
        for (int mi = 0; mi < 2; ++mi)
          #pragma unroll
          for (int ni = 0; ni < 2; ++ni)
            acc[mi][ni] = __builtin_amdgcn_mfma_f32_16x16x32_bf16(a[mi], bb[ni], acc[mi][ni], 0, 0, 0);
        __builtin_amdgcn_s_setprio(0);
      }
      __syncthreads();
      buf ^= 1;
    }

    #pragma unroll
    for (int mi = 0; mi < 2; ++mi) {
      const int mbase = m0 + wr + mi * 16 + kh * 4;
      #pragma unroll
      for (int ni = 0; ni < 2; ++ni) {
        const int nl = nt * 128 + wc + ni * 16 + la;
        const float bn = bias[nl];
        #pragma unroll
        for (int j = 0; j < 4; ++j)
          Co[(size_t)(mbase + j) * 384 + nl] = acc[mi][ni][j] + bn;
      }
    }
  }
}

// ================= fallback (fp32) for small ws =================
__global__ __launch_bounds__(256, 1)
void mha_fused(const float* __restrict__ x, const float* __restrict__ Wq,
               const float* __restrict__ Wk, const float* __restrict__ Wv,
               const float* __restrict__ Wp, const float* __restrict__ bp,
               float* __restrict__ out)
{
  const int bh = blockIdx.x;
  const int b = bh / HEADS, h = bh % HEADS;
  const int tid = (int)threadIdx.x;
  const int wave = tid >> 6, lane = tid & 63;
  const float* xb = x + (size_t)b * TT * EMB;
  const float* wq = Wq + (size_t)h * EMB * DH;
  const float* wk = Wk + (size_t)h * EMB * DH;
  const float* wv = Wv + (size_t)h * EMB * DH;
  __shared__ float Ks[TT][68];
  __shared__ float Vs[TT][64];
  __shared__ float Qt[64][68];
  for (int c = 0; c < 4; ++c) {
    const int s0 = wave * 64 + c * 16;
    float ak[16], av[16];
    #pragma unroll
    for (int r = 0; r < 16; ++r) { ak[r] = 0.f; av[r] = 0.f; }
    for (int e = 0; e < EMB; ++e) {
      const float kk = wk[e * DH + lane];
      const float vv = wv[e * DH + lane];
      #pragma unroll
      for (int r = 0; r < 16; ++r) {
        const float xv = xb[(s0 + r) * EMB + e];
        ak[r] += xv * kk; av[r] += xv * vv;
      }
    }
    #pragma unroll
    for (int r = 0; r < 16; ++r) { Ks[s0 + r][lane] = ak[r]; Vs[s0 + r][lane] = av[r]; }
  }
  __syncthreads();
  const int s = tid;
  float kreg[64];
  {
    const float4* k4 = (const float4*)&Ks[s][0];
    #pragma unroll
    for (int i = 0; i < 16; ++i) {
      float4 kv = k4[i];
      kreg[4*i+0] = kv.x; kreg[4*i+1] = kv.y; kreg[4*i+2] = kv.z; kreg[4*i+3] = kv.w;
    }
  }
  float Lsum = 0.f;
  for (int tile = 0; tile < 4; ++tile) {
    {
      const int r0 = tile * 64 + wave * 16;
      float aq[16];
      #pragma unroll
      for (int r = 0; r < 16; ++r) aq[r] = 0.f;
      for (int e = 0; e < EMB; ++e) {
        const float qw = wq[e * DH + lane];
        #pragma unroll
        for (int r = 0; r < 16; ++r) aq[r] += xb[(r0 + r) * EMB + e] * qw;
      }
      __syncthreads();
      #pragma unroll
      for (int r = 0; r < 16; ++r) Qt[wave*16 + r][lane] = aq[r];
      __syncthreads();
    }
    const int tbase = tile * 64;
    if (tbase + 63 >= s) {
      for (int tr = 0; tr < 64; ++tr) {
        const int t = tbase + tr;
        if (t < s) continue;
        float w = 0.f;
        const float4* q4 = (const float4*)&Qt[tr][0];
        #pragma unroll
        for (int i = 0; i < 16; ++i) {
          float4 qv = q4[i];
          w += qv.x*kreg[4*i+0] + qv.y*kreg[4*i+1] + qv.z*kreg[4*i+2] + qv.w*kreg[4*i+3];
        }
        Lsum += __expf(w * SCALE);
      }
    }
  }
  __syncthreads();
  {
    const float invL = 1.0f / Lsum;
    float4* v4 = (float4*)&Vs[s][0];
    #pragma unroll
    for (int i = 0; i < 16; ++i) {
      float4 vv = v4[i];
      vv.x *= invL; vv.y *= invL; vv.z *= invL; vv.w *= invL;
      v4[i] = vv;
    }
  }
  __syncthreads();
  const float bias1 = bp[tid];
  const float bias2 = (tid < 128) ? bp[256 + tid] : 0.f;
  const int tr = tid >> 2, dq = tid & 3;
  float* ob = out + (size_t)b * TT * EMB;
  for (int tile = 0; tile < 4; ++tile) {
    {
      const int r0 = tile * 64 + wave * 16;
      float aq[16];
      #pragma unroll
      for (int r = 0; r < 16; ++r) aq[r] = 0.f;
      for (int e = 0; e < EMB; ++e) {
        const float qw = wq[e * DH + lane];
        #pragma unroll
        for (int r = 0; r < 16; ++r) aq[r] += xb[(r0 + r) * EMB + e] * qw;
      }
      __syncthreads();
      #pragma unroll
      for (int r = 0; r < 16; ++r) Qt[wave*16 + r][lane] = aq[r];
      __syncthreads();
    }
    const int t = tile * 64 + tr;
    float qreg[16];
    {
      const float4* q4 = (const float4*)&Qt[tr][dq * 16];
      #pragma unroll
      for (int i = 0; i < 4; ++i) {
        float4 qv = q4[i];
        qreg[4*i+0] = qv.x; qreg[4*i+1] = qv.y; qreg[4*i+2] = qv.z; qreg[4*i+3] = qv.w;
      }
    }
    float acc[16];
    #pragma unroll
    for (int i = 0; i < 16; ++i) acc[i] = 0.f;
    for (int s2 = 0; s2 <= t; ++s2) {
      const float4* kk4 = (const float4*)&Ks[s2][dq * 16];
      float part = 0.f;
      #pragma unroll
      for (int i = 0; i < 4; ++i) {
        float4 kv = kk4[i];
        part += qreg[4*i+0]*kv.x + qreg[4*i+1]*kv.y + qreg[4*i+2]*kv.z + qreg[4*i+3]*kv.w;
      }
      part += __shfl_xor(part, 1);
      part += __shfl_xor(part, 2);
      const float p = __expf(part * SCALE);
      const float4* vv4 = (const float4*)&Vs[s2][dq * 16];
      #pragma unroll
      for (int i = 0; i < 4; ++i) {
        float4 vv = vv4[i];
        acc[4*i+0] += p * vv.x; acc[4*i+1] += p * vv.y;
        acc[4*i+2] += p * vv.z; acc[4*i+3] += p * vv.w;
      }
    }
    __syncthreads();
    #pragma unroll
    for (int i = 0; i < 16; ++i) Qt[tr][dq*16 + i] = acc[i];
    __syncthreads();
    const int c1 = tid;
    const int c2 = 256 + tid;
    for (int rg = 0; rg < 4; ++rg) {
      float a1[16], a2[16];
      #pragma unroll
      for (int r = 0; r < 16; ++r) { a1[r] = 0.f; a2[r] = 0.f; }
      for (int d = 0; d < 64; ++d) {
        const float wp1 = Wp[(size_t)(h*64 + d) * EMB + c1];
        const float wp2 = (tid < 128) ? Wp[(size_t)(h*64 + d) * EMB + c2] : 0.f;
        #pragma unroll
        for (int r = 0; r < 16; ++r) {
          const float a = Qt[rg*16 + r][d];
          a1[r] += a * wp1; a2[r] += a * wp2;
        }
      }
      if (h == 0) {
        #pragma unroll
        for (int r = 0; r < 16; ++r) { a1[r] += bias1; a2[r] += bias2; }
      }
      const int trow0 = tile*64 + rg*16;
      #pragma unroll
      for (int r = 0; r < 16; ++r)
        atomicAdd(&ob[(size_t)(trow0 + r) * EMB + c1], a1[r]);
      if (tid < 128) {
        #pragma unroll
        for (int r = 0; r < 16; ++r)
          atomicAdd(&ob[(size_t)(trow0 + r) * EMB + c2], a2[r]);
      }
    }
    __syncthreads();
  }
}

extern "C" void kernel_launch(void* const* d_in, const int* in_sizes, int n_in,
                              void* d_out, int out_size, void* d_ws, size_t ws_size,
                              hipStream_t stream) {
  const float* x  = (const float*)d_in[0];
  const float* Wq = (const float*)d_in[1];
  const float* Wk = (const float*)d_in[2];
  const float* Wv = (const float*)d_in[3];
  const float* Wp = (const float*)d_in[4];
  const float* bp = (const float*)d_in[5];

  const int nb = in_sizes[0] / (TT * EMB);       // batch (128)
  const size_t M = (size_t)nb * TT;              // 32768 rows
  const size_t XB = M * EMB * 2;                 // bf16 activation bytes (25 MB)
  const size_t WT = (size_t)1536 * 384 * 2;

  const size_t off_wt = 0;
  const size_t off_o  = off_wt + WT;
  const size_t need   = off_o + XB;

  if (ws_size < need || nb * HEADS != 768) {
    (void)hipMemsetAsync(d_out, 0, (size_t)out_size * sizeof(float), stream);
    mha_fused<<<nb * HEADS, 256, 0, stream>>>(x, Wq, Wk, Wv, Wp, bp, (float*)d_out);
    return;
  }

  char* ws = (char*)d_ws;
  unsigned short* Wt = (unsigned short*)(ws + off_wt);
  unsigned short* Ow = (unsigned short*)(ws + off_o);

  build_wt<<<288, 256, 0, stream>>>(Wq, Wk, Wv, Wp, Wt);

  qkv_attn<<<nb * HEADS, 1024, 0, stream>>>(x, Wt, Ow);

  proj_gemm<<<(unsigned)(M / 128), 1024, 0, stream>>>(
      Ow, Wt + (size_t)1152 * 384, (float*)d_out, bp);
}